// Round 1
// baseline (780.525 us; speedup 1.0000x reference)
//
#include <hip/hip_runtime.h>
#include <hip/hip_bf16.h>
#include <math.h>

#define BB 32
#define SS 512
#define EE 300
#define FF 100
#define TT 50
#define KK 3
#define ST 32            // s-tile per block in emissions kernel
#define ROWS (ST + 2)    // halo rows for K=3, pad=1
#define EP 301           // padded emb row stride (301 mod 32 = 13, coprime -> no bank conflicts)
#define FP 105           // padded feat stride (105 mod 32 = 9, coprime)

// ---------------------------------------------------------------------------
// Kernel A: emissions[b, s, t] = fc( relu( conv1d( emb[x[b,s]] ) ) )
// grid (S/ST, B), 256 threads. Emb rows for the tile (+halo) staged in LDS.
// ---------------------------------------------------------------------------
__global__ __launch_bounds__(256) void emis_kernel(
    const int* __restrict__ x, const float* __restrict__ emb,
    const float* __restrict__ cw, const float* __restrict__ cb,
    const float* __restrict__ fcw, const float* __restrict__ fcb,
    float* __restrict__ emis)
{
    __shared__ float sh[ROWS * EP];   // 40.9 KB; later reused as feat buffer
    const int tile = blockIdx.x;
    const int b    = blockIdx.y;
    const int s0   = tile * ST;
    const int tid  = threadIdx.x;

    // stage embedding rows (zero rows for conv padding at sequence edges)
    for (int r = 0; r < ROWS; ++r) {
        int src = s0 - 1 + r;
        if (src >= 0 && src < SS) {
            const float* row = emb + (size_t)x[b * SS + src] * EE;
            for (int c = tid; c < EE; c += 256) sh[r * EP + c] = row[c];
        } else {
            for (int c = tid; c < EE; c += 256) sh[r * EP + c] = 0.f;
        }
    }
    __syncthreads();

    // conv: thread (s_l = tid&31, f0 = tid>>5) computes f = f0, f0+8, ... (13 regs)
    const int s_l = tid & 31;
    const int f0  = tid >> 5;      // 0..7
    float acc[13];
#pragma unroll
    for (int m = 0; m < 13; ++m) acc[m] = 0.f;

    const float4* wp = (const float4*)cw;   // each f block: 900 floats = 225 float4 (16B aligned)
    for (int eg = 0; eg < EE / 4; ++eg) {   // groups of 4 e-columns
        const int e0 = eg * 4;
        const float* r0 = sh + (s_l + 0) * EP + e0;
        const float* r1 = sh + (s_l + 1) * EP + e0;
        const float* r2 = sh + (s_l + 2) * EP + e0;
        float a00 = r0[0], a01 = r0[1], a02 = r0[2], a03 = r0[3];
        float a10 = r1[0], a11 = r1[1], a12 = r1[2], a13 = r1[3];
        float a20 = r2[0], a21 = r2[1], a22 = r2[2], a23 = r2[3];
#pragma unroll
        for (int m = 0; m < 13; ++m) {
            int f = f0 + (m << 3);
            if (f < FF) {
                const float4 w0 = wp[f * 225 + 3 * eg + 0];
                const float4 w1 = wp[f * 225 + 3 * eg + 1];
                const float4 w2 = wp[f * 225 + 3 * eg + 2];
                float a = acc[m];
                a = fmaf(a00, w0.x, a); a = fmaf(a10, w0.y, a); a = fmaf(a20, w0.z, a);
                a = fmaf(a01, w0.w, a); a = fmaf(a11, w1.x, a); a = fmaf(a21, w1.y, a);
                a = fmaf(a02, w1.z, a); a = fmaf(a12, w1.w, a); a = fmaf(a22, w2.x, a);
                a = fmaf(a03, w2.y, a); a = fmaf(a13, w2.z, a); a = fmaf(a23, w2.w, a);
                acc[m] = a;
            }
        }
    }
    __syncthreads();   // emb staging no longer needed; reuse LDS as feat

    // feat[s_l][f] = relu(conv + bias)
#pragma unroll
    for (int m = 0; m < 13; ++m) {
        int f = f0 + (m << 3);
        if (f < FF) sh[s_l * FP + f] = fmaxf(acc[m] + cb[f], 0.f);
    }
    __syncthreads();

    // FC: emissions[b, s0+s_l, t] for t = f0, f0+8, ...
    for (int t = f0; t < TT; t += 8) {
        float a = fcb[t];
        const float* w = fcw + t * FF;
        for (int f = 0; f < FF; ++f) a = fmaf(sh[s_l * FP + f], w[f], a);
        emis[((size_t)(b * SS + s0 + s_l)) * TT + t] = a;
    }
}

// ---------------------------------------------------------------------------
// Kernel B: per-batch CRF forward scan + gold-path numerator.
// grid (B), 256 threads. 4 lanes per tag j (j = tid>>2, phase = tid&3).
// ---------------------------------------------------------------------------
__global__ __launch_bounds__(256) void crf_kernel(
    const float* __restrict__ emis, const int* __restrict__ tags,
    const float* __restrict__ start, const float* __restrict__ endt,
    const float* __restrict__ trans, float* __restrict__ nll)
{
    __shared__ float shT[TT * 51];   // trans transposed: shT[j*51 + i] = trans[i][j]
    __shared__ float alphaA[TT], alphaB[TT];
    __shared__ float red[256];
    const int b   = blockIdx.x;
    const int tid = threadIdx.x;

    for (int idx = tid; idx < TT * TT; idx += 256) {
        int i = idx / TT, jj = idx - i * TT;
        shT[jj * 51 + i] = trans[idx];
    }

    // numerator partial sums (emission of gold tag + transition scores)
    float np = 0.f;
    for (int s = tid; s < SS; s += 256) {
        int tg = tags[b * SS + s];
        np += emis[((size_t)(b * SS + s)) * TT + tg];
        if (s < SS - 1) np += trans[tg * TT + tags[b * SS + s + 1]];
    }
    red[tid] = np;
    if (tid < TT) alphaA[tid] = start[tid] + emis[((size_t)(b * SS)) * TT + tid];
    __syncthreads();
    for (int off = 128; off > 0; off >>= 1) {
        if (tid < off) red[tid] += red[tid + off];
        __syncthreads();
    }

    // forward scan
    const int  j   = tid >> 2;
    const int  ph  = tid & 3;
    const bool act = (j < TT);
    float* cur = alphaA;
    float* nxt = alphaB;
    float em_next = act ? emis[((size_t)(b * SS + 1)) * TT + j] : 0.f;

    for (int t = 1; t < SS; ++t) {
        float em_cur = em_next;
        if (act && t + 1 < SS) em_next = emis[((size_t)(b * SS + t + 1)) * TT + j];

        float m = -1e30f, s = 0.f;
        if (act) {
            float v[13];
#pragma unroll
            for (int k = 0; k < 13; ++k) {
                int i = ph + (k << 2);
                v[k] = (i < TT) ? cur[i] + shT[j * 51 + i] : -1e30f;
                m = fmaxf(m, v[k]);
            }
#pragma unroll
            for (int k = 0; k < 13; ++k) s += __expf(v[k] - m);
        }
        // merge the 4 phase-lanes' (m, s) pairs (groups aligned to 4 lanes)
#pragma unroll
        for (int off = 1; off < 4; off <<= 1) {
            float mo = __shfl_xor(m, off);
            float so = __shfl_xor(s, off);
            float mn = fmaxf(m, mo);
            s = s * __expf(m - mn) + so * __expf(mo - mn);
            m = mn;
        }
        if (act && ph == 0) nxt[j] = em_cur + m + __logf(s);
        __syncthreads();
        float* tmp = cur; cur = nxt; nxt = tmp;
    }

    // log_z = logsumexp_j(alpha[j] + end[j]) via wave-0 butterfly
    float lz = 0.f;
    if (tid < 64) {
        float m2 = -1e30f, s2 = 0.f;
        if (tid < TT) { m2 = cur[tid] + endt[tid]; s2 = 1.f; }
#pragma unroll
        for (int off = 1; off < 64; off <<= 1) {
            float mo = __shfl_xor(m2, off);
            float so = __shfl_xor(s2, off);
            float mn = fmaxf(m2, mo);
            s2 = s2 * __expf(m2 - mn) + so * __expf(mo - mn);
            m2 = mn;
        }
        lz = m2 + __logf(s2);
    }
    if (tid == 0) {
        float num = red[0] + start[tags[b * SS]] + endt[tags[b * SS + SS - 1]];
        nll[b] = lz - num;   // -(num - log_z) for this batch
    }
}

// ---------------------------------------------------------------------------
// Kernel C: sum 32 per-batch NLLs -> scalar output (deterministic, no atomics)
// ---------------------------------------------------------------------------
__global__ void sum_kernel(const float* __restrict__ nll, float* __restrict__ out)
{
    int tid = threadIdx.x;
    float v = (tid < BB) ? nll[tid] : 0.f;
#pragma unroll
    for (int off = 1; off < 64; off <<= 1) v += __shfl_xor(v, off);
    if (tid == 0) out[0] = v;
}

extern "C" void kernel_launch(void* const* d_in, const int* in_sizes, int n_in,
                              void* d_out, int out_size, void* d_ws, size_t ws_size,
                              hipStream_t stream)
{
    const int*   x    = (const int*)d_in[0];
    const int*   tags = (const int*)d_in[1];
    const float* emb  = (const float*)d_in[2];
    const float* cw   = (const float*)d_in[3];
    const float* cb   = (const float*)d_in[4];
    const float* fcw  = (const float*)d_in[5];
    const float* fcb  = (const float*)d_in[6];
    const float* st   = (const float*)d_in[7];
    const float* en   = (const float*)d_in[8];
    const float* tr   = (const float*)d_in[9];

    float* emis = (float*)d_ws;                       // B*S*T floats = 3.28 MB
    float* nll  = emis + (size_t)BB * SS * TT;        // 32 floats

    emis_kernel<<<dim3(SS / ST, BB), 256, 0, stream>>>(x, emb, cw, cb, fcw, fcb, emis);
    crf_kernel<<<dim3(BB), 256, 0, stream>>>(emis, tags, st, en, tr, nll);
    sum_kernel<<<dim3(1), 64, 0, stream>>>(nll, (float*)d_out);
}

// Round 2
// 681.957 us; speedup vs baseline: 1.1445x; 1.1445x over previous
//
#include <hip/hip_runtime.h>
#include <hip/hip_bf16.h>
#include <math.h>

#define BB 32
#define SS 512
#define EE 300
#define FF 100
#define TT 50
#define ST 32            // s-tile per block in emissions kernel
#define ROWS (ST + 2)    // halo rows for K=3, pad=1
#define EP 301           // padded emb row stride in LDS
#define FP 105           // padded feat stride
#define TP 53            // padded em-row stride in LDS
#define EPD 56           // padded row stride for E/ET/pf/qb in ws (16B-aligned rows)

// ---------------------------------------------------------------------------
// Kernel 0: E[i][j] = exp(trans[i][j]), ET[j][i] = exp(trans[i][j]) (padded)
// ---------------------------------------------------------------------------
__global__ void prep_kernel(const float* __restrict__ tr,
                            float* __restrict__ E, float* __restrict__ ET)
{
    int tid = threadIdx.x;
    for (int idx = tid; idx < TT * EPD; idx += 256) {
        int i = idx / EPD, j = idx - i * EPD;
        E [idx] = (j < TT) ? __expf(tr[i * TT + j]) : 0.f;
        ET[idx] = (j < TT) ? __expf(tr[j * TT + i]) : 0.f;  // ET row i = trans column i
    }
}

// ---------------------------------------------------------------------------
// Kernel A: emissions -> expem = exp(em - rowmax), rowmax, em[gold tag]
// grid (S/ST, B), 256 threads.
// ---------------------------------------------------------------------------
__global__ __launch_bounds__(256) void emis_kernel(
    const int* __restrict__ x, const float* __restrict__ emb,
    const float* __restrict__ cw, const float* __restrict__ cb,
    const float* __restrict__ fcw, const float* __restrict__ fcb,
    const int* __restrict__ tags,
    float* __restrict__ expem, float* __restrict__ rmv, float* __restrict__ emtag)
{
    __shared__ float sh[ROWS * EP];   // 40.9 KB staging; later carved into feat/em/scratch
    const int tile = blockIdx.x;
    const int b    = blockIdx.y;
    const int s0   = tile * ST;
    const int tid  = threadIdx.x;

    // stage embedding rows (zero rows for conv padding at sequence edges)
    for (int r = 0; r < ROWS; ++r) {
        int src = s0 - 1 + r;
        if (src >= 0 && src < SS) {
            const float* row = emb + (size_t)x[b * SS + src] * EE;
            for (int c = tid; c < EE; c += 256) sh[r * EP + c] = row[c];
        } else {
            for (int c = tid; c < EE; c += 256) sh[r * EP + c] = 0.f;
        }
    }
    __syncthreads();

    // conv: thread (s_l = tid&31, f0 = tid>>5) computes f = f0, f0+8, ...
    const int s_l = tid & 31;
    const int f0  = tid >> 5;      // 0..7
    float acc[13];
#pragma unroll
    for (int m = 0; m < 13; ++m) acc[m] = 0.f;

    const float4* wp = (const float4*)cw;   // each f block: 900 floats = 225 float4
    for (int eg = 0; eg < EE / 4; ++eg) {
        const int e0 = eg * 4;
        const float* r0 = sh + (s_l + 0) * EP + e0;
        const float* r1 = sh + (s_l + 1) * EP + e0;
        const float* r2 = sh + (s_l + 2) * EP + e0;
        float a00 = r0[0], a01 = r0[1], a02 = r0[2], a03 = r0[3];
        float a10 = r1[0], a11 = r1[1], a12 = r1[2], a13 = r1[3];
        float a20 = r2[0], a21 = r2[1], a22 = r2[2], a23 = r2[3];
#pragma unroll
        for (int m = 0; m < 13; ++m) {
            int f = f0 + (m << 3);
            if (f < FF) {
                const float4 w0 = wp[f * 225 + 3 * eg + 0];
                const float4 w1 = wp[f * 225 + 3 * eg + 1];
                const float4 w2 = wp[f * 225 + 3 * eg + 2];
                float a = acc[m];
                a = fmaf(a00, w0.x, a); a = fmaf(a10, w0.y, a); a = fmaf(a20, w0.z, a);
                a = fmaf(a01, w0.w, a); a = fmaf(a11, w1.x, a); a = fmaf(a21, w1.y, a);
                a = fmaf(a02, w1.z, a); a = fmaf(a12, w1.w, a); a = fmaf(a22, w2.x, a);
                a = fmaf(a03, w2.y, a); a = fmaf(a13, w2.z, a); a = fmaf(a23, w2.w, a);
                acc[m] = a;
            }
        }
    }
    __syncthreads();   // staging dead; carve LDS

    float* feat = sh;                          // [32][FP]
    float* emL  = sh + ST * FP;                // [32][TP]
    float* pmax = sh + ST * FP + ST * TP;      // [32][8]
    float* mrow = pmax + ST * 8;               // [32]

#pragma unroll
    for (int m = 0; m < 13; ++m) {
        int f = f0 + (m << 3);
        if (f < FF) feat[s_l * FP + f] = fmaxf(acc[m] + cb[f], 0.f);
    }
    __syncthreads();

    // FC -> em row in LDS + local max
    float lmax = -1e30f;
    for (int t = f0; t < TT; t += 8) {
        float a = fcb[t];
        const float* w = fcw + t * FF;
        for (int f = 0; f < FF; ++f) a = fmaf(feat[s_l * FP + f], w[f], a);
        emL[s_l * TP + t] = a;
        lmax = fmaxf(lmax, a);
    }
    pmax[s_l * 8 + f0] = lmax;
    __syncthreads();

    const int s = s0 + s_l;
    if (f0 == 0) {
        float m = pmax[s_l * 8];
#pragma unroll
        for (int k = 1; k < 8; ++k) m = fmaxf(m, pmax[s_l * 8 + k]);
        mrow[s_l] = m;
        rmv[b * SS + s] = m;
        int tg = tags[b * SS + s];
        emtag[b * SS + s] = emL[s_l * TP + tg];
    }
    __syncthreads();

    float m = mrow[s_l];
    for (int t = f0; t < TT; t += 8)
        expem[((size_t)(b * SS + s)) * TT + t] = __expf(emL[s_l * TP + t] - m);
}

// ---------------------------------------------------------------------------
// Kernel B: probability-domain scan, meet-in-the-middle.
// grid 64 (= B * 2 directions), 64 threads (1 wave). Lane j owns tag j.
// fwd (dir 0): p'_j = (sum_i p_i * ET[j][i]) * expem_t[j],  t = 1..255
// bwd (dir 1): q'_i =  sum_j E[i][j] * (expem_t[j] * q_j),  t = 511..256
// E-row in 56 VGPRs; p/w in double-buffered LDS row, broadcast float4 reads.
// ---------------------------------------------------------------------------
__global__ __launch_bounds__(64) void scan_kernel(
    const float* __restrict__ expem, const float* __restrict__ Emat,
    const float* __restrict__ ETmat,
    const float* __restrict__ start, const float* __restrict__ endt,
    float* __restrict__ pf, float* __restrict__ qb, float* __restrict__ rlog)
{
    __shared__ __align__(16) float buf[2][EPD];
    const int  b   = blockIdx.x >> 1;
    const int  dir = blockIdx.x & 1;
    const int  j   = threadIdx.x;
    const bool act = (j < TT);

    // E row into registers (fwd uses ET, bwd uses E); inactive lanes zero
    float4 frag[14];
    const float4* er = (const float4*)((dir ? Emat : ETmat) + j * EPD);
#pragma unroll
    for (int k = 0; k < 14; ++k)
        frag[k] = act ? er[k] : make_float4(0.f, 0.f, 0.f, 0.f);

    const float* em_b = expem + (size_t)b * SS * TT;
    float logacc = 0.f;

    if (j < EPD) { buf[0][j] = 0.f; buf[1][j] = 0.f; }

    if (dir == 0) {
        // ---- forward ----
        float p0 = act ? __expf(start[j]) * em_b[j] : 0.f;
        if (j < EPD) buf[0][j] = (act ? p0 : 0.f);
        __syncthreads();
        float e_cur = act ? em_b[(size_t)TT + j] : 0.f;   // expem at t=1
        int cur = 0;
        float plast = p0;
        for (int t = 1; t <= 255; ++t) {
            float e_next = (act && t < 255) ? em_b[(size_t)(t + 1) * TT + j] : 0.f;
            const float4* pb = (const float4*)buf[cur];
            float d0 = 0.f, d1 = 0.f, d2 = 0.f, d3 = 0.f;
#pragma unroll
            for (int k = 0; k < 14; ++k) {
                float4 pv = pb[k];
                d0 = fmaf(pv.x, frag[k].x, d0); d1 = fmaf(pv.y, frag[k].y, d1);
                d2 = fmaf(pv.z, frag[k].z, d2); d3 = fmaf(pv.w, frag[k].w, d3);
            }
            float p = ((d0 + d1) + (d2 + d3)) * e_cur;
            if ((t & 7) == 0) {           // renormalize by wave-max
                float m = p;
#pragma unroll
                for (int off = 1; off < 64; off <<= 1) m = fmaxf(m, __shfl_xor(m, off));
                m = fmaxf(m, 1e-37f);
                p *= (1.f / m);
                logacc += __logf(m);
            }
            if (act) buf[cur ^ 1][j] = p;
            __syncthreads();
            cur ^= 1;
            e_cur = e_next;
            plast = p;
        }
        if (act) pf[b * EPD + j] = plast;
        if (j == 0) rlog[2 * b] = logacc;
    } else {
        // ---- backward ----
        __syncthreads();
        float q = act ? __expf(endt[j]) : 0.f;
        float e_cur = act ? em_b[(size_t)511 * TT + j] : 0.f;
        int cur = 0;
        for (int t = 511; t >= 256; --t) {
            float e_next = (act && t > 256) ? em_b[(size_t)(t - 1) * TT + j] : 0.f;
            if (act) buf[cur][j] = q * e_cur;
            __syncthreads();
            const float4* wb = (const float4*)buf[cur];
            float d0 = 0.f, d1 = 0.f, d2 = 0.f, d3 = 0.f;
#pragma unroll
            for (int k = 0; k < 14; ++k) {
                float4 wv = wb[k];
                d0 = fmaf(wv.x, frag[k].x, d0); d1 = fmaf(wv.y, frag[k].y, d1);
                d2 = fmaf(wv.z, frag[k].z, d2); d3 = fmaf(wv.w, frag[k].w, d3);
            }
            q = (d0 + d1) + (d2 + d3);
            if ((t & 7) == 0) {
                float m = q;
#pragma unroll
                for (int off = 1; off < 64; off <<= 1) m = fmaxf(m, __shfl_xor(m, off));
                m = fmaxf(m, 1e-37f);
                q *= (1.f / m);
                logacc += __logf(m);
            }
            cur ^= 1;
            e_cur = e_next;
        }
        if (act) qb[b * EPD + j] = q;
        if (j == 0) rlog[2 * b + 1] = logacc;
    }
}

// ---------------------------------------------------------------------------
// Kernel C: numerator + combine + total sum -> scalar
// grid 1, 256 threads: 8 threads per batch.
// ---------------------------------------------------------------------------
__global__ __launch_bounds__(256) void final_kernel(
    const float* __restrict__ emtag, const float* __restrict__ rmv,
    const int* __restrict__ tags, const float* __restrict__ tr,
    const float* __restrict__ start, const float* __restrict__ endt,
    const float* __restrict__ pf, const float* __restrict__ qb,
    const float* __restrict__ rlog, float* __restrict__ out)
{
    __shared__ float redN[256], redR[256], nllsh[BB];
    const int tid = threadIdx.x;
    const int b   = tid >> 3;
    const int sl  = tid & 7;
    const int base = b * SS + sl * 64;

    float accN = 0.f, accR = 0.f;
    for (int k = 0; k < 64; ++k) {
        int s = sl * 64 + k;
        accN += emtag[base + k];
        accR += rmv[base + k];
        int tg = tags[base + k];
        if (s < SS - 1) accN += tr[tg * TT + tags[base + k + 1]];
    }
    redN[tid] = accN; redR[tid] = accR;
    __syncthreads();

    if (sl == 0) {
        float tn = 0.f, trm = 0.f;
#pragma unroll
        for (int k = 0; k < 8; ++k) { tn += redN[b * 8 + k]; trm += redR[b * 8 + k]; }
        float dot = 0.f;
        for (int jj = 0; jj < TT; ++jj) dot = fmaf(pf[b * EPD + jj], qb[b * EPD + jj], dot);
        float num = tn + start[tags[b * SS]] + endt[tags[b * SS + SS - 1]];
        float lz  = trm + rlog[2 * b] + rlog[2 * b + 1] + __logf(dot);
        nllsh[b] = lz - num;
    }
    __syncthreads();
    if (tid < 64) {
        float v = (tid < BB) ? nllsh[tid] : 0.f;
#pragma unroll
        for (int off = 1; off < 64; off <<= 1) v += __shfl_xor(v, off);
        if (tid == 0) out[0] = v;
    }
}

extern "C" void kernel_launch(void* const* d_in, const int* in_sizes, int n_in,
                              void* d_out, int out_size, void* d_ws, size_t ws_size,
                              hipStream_t stream)
{
    const int*   x    = (const int*)d_in[0];
    const int*   tags = (const int*)d_in[1];
    const float* emb  = (const float*)d_in[2];
    const float* cw   = (const float*)d_in[3];
    const float* cb   = (const float*)d_in[4];
    const float* fcw  = (const float*)d_in[5];
    const float* fcb  = (const float*)d_in[6];
    const float* st   = (const float*)d_in[7];
    const float* en   = (const float*)d_in[8];
    const float* tr   = (const float*)d_in[9];

    float* w      = (float*)d_ws;
    float* expem  = w;                              // 819200
    float* rmv    = expem + (size_t)BB * SS * TT;   // 16384
    float* emtag  = rmv + BB * SS;                  // 16384
    float* Emat   = emtag + BB * SS;                // 2800
    float* ETmat  = Emat + TT * EPD;                // 2800
    float* pf     = ETmat + TT * EPD;               // 1792
    float* qb     = pf + BB * EPD;                  // 1792
    float* rlog   = qb + BB * EPD;                  // 64

    prep_kernel<<<dim3(1), 256, 0, stream>>>(tr, Emat, ETmat);
    emis_kernel<<<dim3(SS / ST, BB), 256, 0, stream>>>(x, emb, cw, cb, fcw, fcb,
                                                       tags, expem, rmv, emtag);
    scan_kernel<<<dim3(2 * BB), 64, 0, stream>>>(expem, Emat, ETmat, st, en, pf, qb, rlog);
    final_kernel<<<dim3(1), 256, 0, stream>>>(emtag, rmv, tags, tr, st, en,
                                              pf, qb, rlog, (float*)d_out);
}

// Round 3
// 456.662 us; speedup vs baseline: 1.7092x; 1.4934x over previous
//
#include <hip/hip_runtime.h>
#include <hip/hip_bf16.h>
#include <math.h>

#define BB 32
#define SS 512
#define EE 300
#define FF 100
#define TT 50
#define EPD 56           // padded row stride for E/ET/pf/qb (floats, 16B-aligned)

// MFMA types
typedef __attribute__((ext_vector_type(8))) short v8s;   // 8 bf16
typedef __attribute__((ext_vector_type(4))) float v4f;   // 4 f32
#define MFMA16 __builtin_amdgcn_mfma_f32_16x16x32_bf16

// A (emb) LDS: 34 rows x 328 bf16 (stride 328: 164 words, /4=41, odd -> even bank-groups)
#define AP 328
// B (weights) LDS: 128 f x 160 bf16 (stride 160: 80 words, /4=20 -> even bank-groups)
#define BKC 160          // K-chunk
// FC LDS strides
#define A2P 136          // 68 words, /4=17, odd -> OK

__device__ inline unsigned short f2bf(float v) {
    unsigned u = __float_as_uint(v);
    unsigned r = u + 0x7fff + ((u >> 16) & 1);   // round-to-nearest-even
    return (unsigned short)(r >> 16);
}

__device__ inline v8s ldsld8(const short* p) {
    return *(const v8s*)__builtin_assume_aligned(p, 16);
}

__device__ inline void g2lds16(const void* g, void* l) {
    __builtin_amdgcn_global_load_lds(
        (const __attribute__((address_space(1))) unsigned int*)g,
        (__attribute__((address_space(3))) unsigned int*)l, 16, 0, 0);
}

// ---------------------------------------------------------------------------
// Kernel 0: build exp(trans) tables (f32) + bf16 weight layouts.
// wB2 chunk-major: wB2[c][f][j] = bf16(cw[f][e][kk]), gk=c*160+j, kk=gk/320, e=gk%320
// fcwT2: [64 t][136 f] bf16, zero-padded.
// ---------------------------------------------------------------------------
__global__ void prep_kernel(const float* __restrict__ tr, const float* __restrict__ cw,
                            const float* __restrict__ fcw,
                            float* __restrict__ E, float* __restrict__ ET,
                            unsigned short* __restrict__ wB2,
                            unsigned short* __restrict__ fcwT2)
{
    const int gid = blockIdx.x * 256 + threadIdx.x;
    const int gs  = 64 * 256;
    for (int idx = gid; idx < TT * EPD; idx += gs) {
        int i = idx / EPD, j = idx - i * EPD;
        E [idx] = (j < TT) ? __expf(tr[i * TT + j]) : 0.f;
        ET[idx] = (j < TT) ? __expf(tr[j * TT + i]) : 0.f;
    }
    for (int idx = gid; idx < 6 * 128 * BKC; idx += gs) {
        int c = idx / (128 * BKC); int r = idx - c * 128 * BKC;
        int f = r / BKC; int j = r - f * BKC;
        int gk = c * BKC + j; int kk = gk / 320; int e = gk - kk * 320;
        float v = (f < FF && e < EE) ? cw[f * 900 + e * 3 + kk] : 0.f;
        wB2[idx] = f2bf(v);
    }
    for (int idx = gid; idx < 64 * A2P; idx += gs) {
        int t = idx / A2P, f = idx - t * A2P;
        float v = (t < TT && f < FF) ? fcw[t * FF + f] : 0.f;
        fcwT2[idx] = f2bf(v);
    }
}

// ---------------------------------------------------------------------------
// Kernel A: MFMA conv(K=3) + FC, fused epilogue -> expem/rmv/emtag.
// grid (16, 32) = 512 blocks (32 s per block), 256 threads (4 waves).
// Conv GEMM: A[s][kk*320+e] = emb[x[s+kk-1]][e] (bf16 LDS), B staged per K-chunk
// via global_load_lds from prep-built wB2. Wave w: both s-tiles x f-tiles {2w,2w+1}.
// ---------------------------------------------------------------------------
__global__ __launch_bounds__(256, 2) void emis_kernel(
    const int* __restrict__ x, const float* __restrict__ emb,
    const unsigned short* __restrict__ wB2, const float* __restrict__ cb,
    const unsigned short* __restrict__ fcwT2, const float* __restrict__ fcb,
    const int* __restrict__ tags,
    float* __restrict__ expem, float* __restrict__ rmv, float* __restrict__ emtag)
{
    __shared__ __align__(16) short ldsA[34 * AP];     // 22304 B
    __shared__ __align__(16) short ldsB[128 * BKC];   // 40960 B (reused for FC)

    const int b   = blockIdx.y;
    const int s0  = blockIdx.x * 32;
    const int tid = threadIdx.x;
    const int wv  = tid >> 6;
    const int lane = tid & 63;
    const int col = lane & 15;
    const int q   = lane >> 4;

    // ---- stage A: 34 emb rows -> bf16, zero halo rows + zero cols 300..319
    for (int g = tid; g < 34 * 75; g += 256) {
        int r = g / 75, eg = g - r * 75; int e0 = eg * 4;
        int gsq = s0 - 1 + r;
        short4 o;
        if (gsq >= 0 && gsq < SS) {
            int xr = x[b * SS + gsq];
            const float4 v = *(const float4*)(emb + (size_t)xr * EE + e0);
            o = make_short4((short)f2bf(v.x), (short)f2bf(v.y),
                            (short)f2bf(v.z), (short)f2bf(v.w));
        } else o = make_short4(0, 0, 0, 0);
        *(short4*)&ldsA[r * AP + e0] = o;
    }
    if (tid < 34 * 5) {
        int r = tid / 5, c0 = 300 + (tid % 5) * 4;
        *(short4*)&ldsA[r * AP + c0] = make_short4(0, 0, 0, 0);
    }

    // ---- conv main loop: 6 K-chunks of 160
    v4f acc[2][2];
#pragma unroll
    for (int a = 0; a < 2; ++a)
#pragma unroll
        for (int f = 0; f < 2; ++f) acc[a][f] = (v4f){0.f, 0.f, 0.f, 0.f};

    const int ftA = wv * 2, ftB = wv * 2 + 1;
    for (int ch = 0; ch < 6; ++ch) {
        const char* gsrc = (const char*)(wB2 + (size_t)ch * 128 * BKC);
#pragma unroll
        for (int it = 0; it < 10; ++it) {
            int seg = it * 4 + wv;
            g2lds16(gsrc + seg * 1024 + lane * 16, (char*)ldsB + seg * 1024);
        }
        __syncthreads();
#pragma unroll
        for (int sl = 0; sl < 5; ++sl) {
            int gk = ch * BKC + sl * 32;
            int kk = gk / 320;
            int e0 = gk - kk * 320;
            v8s a0 = ldsld8(&ldsA[(col + kk) * AP + e0 + q * 8]);
            v8s a1 = ldsld8(&ldsA[(16 + col + kk) * AP + e0 + q * 8]);
            v8s b0 = ldsld8(&ldsB[(ftA * 16 + col) * BKC + sl * 32 + q * 8]);
            v8s b1 = ldsld8(&ldsB[(ftB * 16 + col) * BKC + sl * 32 + q * 8]);
            acc[0][0] = MFMA16(a0, b0, acc[0][0], 0, 0, 0);
            acc[0][1] = MFMA16(a0, b1, acc[0][1], 0, 0, 0);
            acc[1][0] = MFMA16(a1, b0, acc[1][0], 0, 0, 0);
            acc[1][1] = MFMA16(a1, b1, acc[1][1], 0, 0, 0);
        }
        __syncthreads();
    }

    // ---- bias + relu -> feat (bf16) into LDS (A2), stage fcwT2 (B2)
    short* A2 = ldsB;                 // 32 x A2P
    short* B2 = ldsB + 32 * A2P;      // 64 x A2P (17408 B)
#pragma unroll
    for (int st = 0; st < 2; ++st)
#pragma unroll
        for (int fi = 0; fi < 2; ++fi) {
            int f = (wv * 2 + fi) * 16 + col;
            float bias = (f < FF) ? cb[f] : 0.f;
#pragma unroll
            for (int rg = 0; rg < 4; ++rg) {
                int s = st * 16 + q * 4 + rg;
                float v = (f < FF) ? fmaxf(acc[st][fi][rg] + bias, 0.f) : 0.f;
                A2[s * A2P + f] = (short)f2bf(v);
            }
        }
#pragma unroll
    for (int it = 0; it < 5; ++it) {
        int seg = it * 4 + wv;
        if (seg < 17) g2lds16((const char*)fcwT2 + seg * 1024 + lane * 16,
                              (char*)B2 + seg * 1024);
    }
    __syncthreads();

    // ---- FC MFMA + epilogue (waves 0,1; wave = s-tile)
    if (wv < 2) {
        v4f a2[4];
#pragma unroll
        for (int nt = 0; nt < 4; ++nt) a2[nt] = (v4f){0.f, 0.f, 0.f, 0.f};
#pragma unroll
        for (int ks = 0; ks < 4; ++ks) {
            v8s af = ldsld8(&A2[(wv * 16 + col) * A2P + ks * 32 + q * 8]);
#pragma unroll
            for (int nt = 0; nt < 4; ++nt) {
                v8s bt = ldsld8(&B2[(nt * 16 + col) * A2P + ks * 32 + q * 8]);
                a2[nt] = MFMA16(af, bt, a2[nt], 0, 0, 0);
            }
        }
        float fb0 = fcb[col], fb1 = fcb[16 + col], fb2 = fcb[32 + col];
        float fb3 = (col < 2) ? fcb[48 + col] : 0.f;
#pragma unroll
        for (int rg = 0; rg < 4; ++rg) {
            int s = s0 + wv * 16 + q * 4 + rg;
            float e0v = a2[0][rg] + fb0;
            float e1v = a2[1][rg] + fb1;
            float e2v = a2[2][rg] + fb2;
            float e3v = (col < 2) ? a2[3][rg] + fb3 : -1e30f;
            float m = fmaxf(fmaxf(e0v, e1v), fmaxf(e2v, e3v));
#pragma unroll
            for (int off = 1; off < 16; off <<= 1) m = fmaxf(m, __shfl_xor(m, off));
            int gidx = b * SS + s;
            if (col == 0) rmv[gidx] = m;
            int tg = tags[gidx];
            float* orow = expem + (size_t)gidx * TT;
            orow[col]      = __expf(e0v - m);
            orow[16 + col] = __expf(e1v - m);
            orow[32 + col] = __expf(e2v - m);
            if (col < 2) orow[48 + col] = __expf(e3v - m);
            if (tg == col)            emtag[gidx] = e0v;
            else if (tg == 16 + col)  emtag[gidx] = e1v;
            else if (tg == 32 + col)  emtag[gidx] = e2v;
            else if (col < 2 && tg == 48 + col) emtag[gidx] = e3v;
        }
    }
}

// ---------------------------------------------------------------------------
// Kernel B: probability-domain scan, fwd+bwd chains FUSED in one wave.
// grid 32 (one block per batch), 64 threads. Lane j owns tag j.
// ---------------------------------------------------------------------------
__global__ __launch_bounds__(64, 1) void scan_kernel(
    const float* __restrict__ expem, const float* __restrict__ Emat,
    const float* __restrict__ ETmat,
    const float* __restrict__ start, const float* __restrict__ endt,
    float* __restrict__ pf, float* __restrict__ qb, float* __restrict__ rlog)
{
    __shared__ __align__(16) float bufF[2][EPD], bufB[2][EPD];
    const int  b   = blockIdx.x;
    const int  j   = threadIdx.x;
    const bool act = (j < TT);

    float4 fF[14], fB[14];
    const float4* eT = (const float4*)(ETmat + j * EPD);
    const float4* eM = (const float4*)(Emat  + j * EPD);
#pragma unroll
    for (int k = 0; k < 14; ++k) {
        fF[k] = act ? eT[k] : make_float4(0.f, 0.f, 0.f, 0.f);
        fB[k] = act ? eM[k] : make_float4(0.f, 0.f, 0.f, 0.f);
    }

    const float* em_b = expem + (size_t)b * SS * TT;
    float laF = 0.f, laB = 0.f;

    float p  = act ? __expf(start[j]) * em_b[j] : 0.f;
    float qw = act ? __expf(endt[j]) * em_b[(size_t)511 * TT + j] : 0.f;
    if (j < EPD) {
        bufF[0][j] = act ? p  : 0.f;  bufF[1][j] = 0.f;
        bufB[0][j] = act ? qw : 0.f;  bufB[1][j] = 0.f;
    }
    __syncthreads();

    float efc = act ? em_b[(size_t)TT + j] : 0.f;          // em for fwd t=1
    float ebc = act ? em_b[(size_t)510 * TT + j] : 0.f;    // em for bwd write (t=510)
    int cur = 0;
    float qv = 0.f;
    for (int k = 1; k <= 255; ++k) {
        float efn = (act && k < 255) ? em_b[(size_t)(k + 1) * TT + j] : 0.f;
        float ebn = (act && k < 255) ? em_b[(size_t)(510 - k) * TT + j] : 0.f;
        const float4* pb = (const float4*)bufF[cur];
        const float4* wb = (const float4*)bufB[cur];
        float d0 = 0.f, d1 = 0.f, d2 = 0.f, d3 = 0.f;
        float g0 = 0.f, g1 = 0.f, g2 = 0.f, g3 = 0.f;
#pragma unroll
        for (int k2 = 0; k2 < 14; ++k2) {
            float4 pv = pb[k2], wv2 = wb[k2];
            d0 = fmaf(pv.x, fF[k2].x, d0);  g0 = fmaf(wv2.x, fB[k2].x, g0);
            d1 = fmaf(pv.y, fF[k2].y, d1);  g1 = fmaf(wv2.y, fB[k2].y, g1);
            d2 = fmaf(pv.z, fF[k2].z, d2);  g2 = fmaf(wv2.z, fB[k2].z, g2);
            d3 = fmaf(pv.w, fF[k2].w, d3);  g3 = fmaf(wv2.w, fB[k2].w, g3);
        }
        p  = ((d0 + d1) + (d2 + d3)) * efc;
        qv = (g0 + g1) + (g2 + g3);
        if ((k & 7) == 0) {
            float mF = p, mB = qv;
#pragma unroll
            for (int off = 1; off < 64; off <<= 1) {
                mF = fmaxf(mF, __shfl_xor(mF, off));
                mB = fmaxf(mB, __shfl_xor(mB, off));
            }
            mF = fmaxf(mF, 1e-37f); mB = fmaxf(mB, 1e-37f);
            p  *= (1.f / mF);  laF += __logf(mF);
            qv *= (1.f / mB);  laB += __logf(mB);
        }
        if (act) { bufF[cur ^ 1][j] = p; bufB[cur ^ 1][j] = qv * ebc; }
        __syncthreads();
        cur ^= 1;
        efc = efn; ebc = ebn;
    }
    // final bwd step (consume t=256)
    {
        const float4* wb = (const float4*)bufB[cur];
        float g0 = 0.f, g1 = 0.f, g2 = 0.f, g3 = 0.f;
#pragma unroll
        for (int k2 = 0; k2 < 14; ++k2) {
            float4 wv2 = wb[k2];
            g0 = fmaf(wv2.x, fB[k2].x, g0); g1 = fmaf(wv2.y, fB[k2].y, g1);
            g2 = fmaf(wv2.z, fB[k2].z, g2); g3 = fmaf(wv2.w, fB[k2].w, g3);
        }
        qv = (g0 + g1) + (g2 + g3);
    }
    if (act) { pf[b * EPD + j] = p; qb[b * EPD + j] = qv; }
    if (j == 0) { rlog[2 * b] = laF; rlog[2 * b + 1] = laB; }
}

// ---------------------------------------------------------------------------
// Kernel C: numerator + combine + total sum -> scalar
// ---------------------------------------------------------------------------
__global__ __launch_bounds__(256) void final_kernel(
    const float* __restrict__ emtag, const float* __restrict__ rmv,
    const int* __restrict__ tags, const float* __restrict__ tr,
    const float* __restrict__ start, const float* __restrict__ endt,
    const float* __restrict__ pf, const float* __restrict__ qb,
    const float* __restrict__ rlog, float* __restrict__ out)
{
    __shared__ float redN[256], redR[256], nllsh[BB];
    const int tid = threadIdx.x;
    const int b   = tid >> 3;
    const int sl  = tid & 7;
    const int base = b * SS + sl * 64;

    float accN = 0.f, accR = 0.f;
    for (int k = 0; k < 64; ++k) {
        int s = sl * 64 + k;
        accN += emtag[base + k];
        accR += rmv[base + k];
        int tg = tags[base + k];
        if (s < SS - 1) accN += tr[tg * TT + tags[base + k + 1]];
    }
    redN[tid] = accN; redR[tid] = accR;
    __syncthreads();

    if (sl == 0) {
        float tn = 0.f, trm = 0.f;
#pragma unroll
        for (int k = 0; k < 8; ++k) { tn += redN[b * 8 + k]; trm += redR[b * 8 + k]; }
        float dot = 0.f;
        for (int jj = 0; jj < TT; ++jj) dot = fmaf(pf[b * EPD + jj], qb[b * EPD + jj], dot);
        float num = tn + start[tags[b * SS]] + endt[tags[b * SS + SS - 1]];
        float lz  = trm + rlog[2 * b] + rlog[2 * b + 1] + __logf(dot);
        nllsh[b] = lz - num;
    }
    __syncthreads();
    if (tid < 64) {
        float v = (tid < BB) ? nllsh[tid] : 0.f;
#pragma unroll
        for (int off = 1; off < 64; off <<= 1) v += __shfl_xor(v, off);
        if (tid == 0) out[0] = v;
    }
}

extern "C" void kernel_launch(void* const* d_in, const int* in_sizes, int n_in,
                              void* d_out, int out_size, void* d_ws, size_t ws_size,
                              hipStream_t stream)
{
    const int*   x    = (const int*)d_in[0];
    const int*   tags = (const int*)d_in[1];
    const float* emb  = (const float*)d_in[2];
    const float* cw   = (const float*)d_in[3];
    const float* cb   = (const float*)d_in[4];
    const float* fcw  = (const float*)d_in[5];
    const float* fcb  = (const float*)d_in[6];
    const float* st   = (const float*)d_in[7];
    const float* en   = (const float*)d_in[8];
    const float* tr   = (const float*)d_in[9];

    unsigned short* wB2   = (unsigned short*)d_ws;                 // 122880 sh
    unsigned short* fcwT2 = wB2 + 6 * 128 * BKC;                   // 8704 sh
    float* fbase = (float*)((char*)d_ws + (6 * 128 * BKC + 64 * A2P) * 2);
    float* expem  = fbase;                           // 819200
    float* rmv    = expem + (size_t)BB * SS * TT;    // 16384
    float* emtag  = rmv + BB * SS;                   // 16384
    float* Emat   = emtag + BB * SS;                 // 2800
    float* ETmat  = Emat + TT * EPD;                 // 2800
    float* pf     = ETmat + TT * EPD;                // 1792
    float* qb     = pf + BB * EPD;                   // 1792
    float* rlog   = qb + BB * EPD;                   // 64

    prep_kernel<<<dim3(64), 256, 0, stream>>>(tr, cw, fcw, Emat, ETmat, wB2, fcwT2);
    emis_kernel<<<dim3(16, BB), 256, 0, stream>>>(x, emb, wB2, cb, fcwT2, fcb,
                                                  tags, expem, rmv, emtag);
    scan_kernel<<<dim3(BB), 64, 0, stream>>>(expem, Emat, ETmat, st, en, pf, qb, rlog);
    final_kernel<<<dim3(1), 256, 0, stream>>>(emtag, rmv, tags, tr, st, en,
                                              pf, qb, rlog, (float*)d_out);
}

// Round 4
// 256.461 us; speedup vs baseline: 3.0435x; 1.7806x over previous
//
#include <hip/hip_runtime.h>
#include <hip/hip_bf16.h>
#include <math.h>

#define BB 32
#define SS 512
#define EE 300
#define FF 100
#define TT 50
#define CH 16            // steps per chunk (15 multiplies; growth bound safe w/o renorm)
#define NC 32            // chunks = 512/16

// MFMA types
typedef __attribute__((ext_vector_type(8))) short v8s;   // 8 bf16
typedef __attribute__((ext_vector_type(4))) float v4f;   // 4 f32
#define MFMA16 __builtin_amdgcn_mfma_f32_16x16x32_bf16

#define AP 328           // emb LDS stride (bf16)
#define BKC 160          // conv weight K-chunk
#define A2P 136          // FC LDS stride
#define MP 72            // chunk-product LDS row stride (bf16): 36 words -> 2-way max (free)

__device__ inline unsigned short f2bf(float v) {
    unsigned u = __float_as_uint(v);
    unsigned r = u + 0x7fff + ((u >> 16) & 1);
    return (unsigned short)(r >> 16);
}
__device__ inline float bf2f(short s) {
    return __uint_as_float(((unsigned)(unsigned short)s) << 16);
}
__device__ inline v8s ldsld8(const short* p) {
    return *(const v8s*)__builtin_assume_aligned(p, 16);
}
__device__ inline void g2lds16(const void* g, void* l) {
    __builtin_amdgcn_global_load_lds(
        (const __attribute__((address_space(1))) unsigned int*)g,
        (__attribute__((address_space(3))) unsigned int*)l, 16, 0, 0);
}

// ---------------------------------------------------------------------------
// Kernel 0: bf16 conv/fc weight layouts + bf16 exp(trans) matrices.
// AT[j*64+i] = exp(trans[i][j])  (A^T, row-major, 64x64 zero-padded)
// Ab[n*64+j] = exp(trans[n][j])  (A,   row-major, 64x64 zero-padded)
// ---------------------------------------------------------------------------
__global__ void prep_kernel(const float* __restrict__ tr, const float* __restrict__ cw,
                            const float* __restrict__ fcw,
                            unsigned short* __restrict__ wB2,
                            unsigned short* __restrict__ fcwT2,
                            unsigned short* __restrict__ AT,
                            unsigned short* __restrict__ Ab)
{
    const int gid = blockIdx.x * 256 + threadIdx.x;
    const int gs  = 64 * 256;
    for (int idx = gid; idx < 6 * 128 * BKC; idx += gs) {
        int c = idx / (128 * BKC); int r = idx - c * 128 * BKC;
        int f = r / BKC; int j = r - f * BKC;
        int gk = c * BKC + j; int kk = gk / 320; int e = gk - kk * 320;
        float v = (f < FF && e < EE) ? cw[f * 900 + e * 3 + kk] : 0.f;
        wB2[idx] = f2bf(v);
    }
    for (int idx = gid; idx < 64 * A2P; idx += gs) {
        int t = idx / A2P, f = idx - t * A2P;
        float v = (t < TT && f < FF) ? fcw[t * FF + f] : 0.f;
        fcwT2[idx] = f2bf(v);
    }
    for (int idx = gid; idx < 64 * 64; idx += gs) {
        int r = idx >> 6, c2 = idx & 63;
        AT[idx] = (r < TT && c2 < TT) ? f2bf(__expf(tr[c2 * TT + r])) : 0;
        Ab[idx] = (r < TT && c2 < TT) ? f2bf(__expf(tr[r * TT + c2])) : 0;
    }
}

// ---------------------------------------------------------------------------
// Kernel A: MFMA conv(K=3) + FC, fused epilogue -> expem/rmv/emtag. (as R3)
// ---------------------------------------------------------------------------
__global__ __launch_bounds__(256, 2) void emis_kernel(
    const int* __restrict__ x, const float* __restrict__ emb,
    const unsigned short* __restrict__ wB2, const float* __restrict__ cb,
    const unsigned short* __restrict__ fcwT2, const float* __restrict__ fcb,
    const int* __restrict__ tags,
    float* __restrict__ expem, float* __restrict__ rmv, float* __restrict__ emtag)
{
    __shared__ __align__(16) short ldsA[34 * AP];
    __shared__ __align__(16) short ldsB[128 * BKC];

    const int b   = blockIdx.y;
    const int s0  = blockIdx.x * 32;
    const int tid = threadIdx.x;
    const int wv  = tid >> 6;
    const int lane = tid & 63;
    const int col = lane & 15;
    const int q   = lane >> 4;

    for (int g = tid; g < 34 * 75; g += 256) {
        int r = g / 75, eg = g - r * 75; int e0 = eg * 4;
        int gsq = s0 - 1 + r;
        short4 o;
        if (gsq >= 0 && gsq < SS) {
            int xr = x[b * SS + gsq];
            const float4 v = *(const float4*)(emb + (size_t)xr * EE + e0);
            o = make_short4((short)f2bf(v.x), (short)f2bf(v.y),
                            (short)f2bf(v.z), (short)f2bf(v.w));
        } else o = make_short4(0, 0, 0, 0);
        *(short4*)&ldsA[r * AP + e0] = o;
    }
    if (tid < 34 * 5) {
        int r = tid / 5, c0 = 300 + (tid % 5) * 4;
        *(short4*)&ldsA[r * AP + c0] = make_short4(0, 0, 0, 0);
    }

    v4f acc[2][2];
#pragma unroll
    for (int a = 0; a < 2; ++a)
#pragma unroll
        for (int f = 0; f < 2; ++f) acc[a][f] = (v4f){0.f, 0.f, 0.f, 0.f};

    const int ftA = wv * 2, ftB = wv * 2 + 1;
    for (int ch = 0; ch < 6; ++ch) {
        const char* gsrc = (const char*)(wB2 + (size_t)ch * 128 * BKC);
#pragma unroll
        for (int it = 0; it < 10; ++it) {
            int seg = it * 4 + wv;
            g2lds16(gsrc + seg * 1024 + lane * 16, (char*)ldsB + seg * 1024);
        }
        __syncthreads();
#pragma unroll
        for (int sl = 0; sl < 5; ++sl) {
            int gk = ch * BKC + sl * 32;
            int kk = gk / 320;
            int e0 = gk - kk * 320;
            v8s a0 = ldsld8(&ldsA[(col + kk) * AP + e0 + q * 8]);
            v8s a1 = ldsld8(&ldsA[(16 + col + kk) * AP + e0 + q * 8]);
            v8s b0 = ldsld8(&ldsB[(ftA * 16 + col) * BKC + sl * 32 + q * 8]);
            v8s b1 = ldsld8(&ldsB[(ftB * 16 + col) * BKC + sl * 32 + q * 8]);
            acc[0][0] = MFMA16(a0, b0, acc[0][0], 0, 0, 0);
            acc[0][1] = MFMA16(a0, b1, acc[0][1], 0, 0, 0);
            acc[1][0] = MFMA16(a1, b0, acc[1][0], 0, 0, 0);
            acc[1][1] = MFMA16(a1, b1, acc[1][1], 0, 0, 0);
        }
        __syncthreads();
    }

    short* A2 = ldsB;
    short* B2 = ldsB + 32 * A2P;
#pragma unroll
    for (int st = 0; st < 2; ++st)
#pragma unroll
        for (int fi = 0; fi < 2; ++fi) {
            int f = (wv * 2 + fi) * 16 + col;
            float bias = (f < FF) ? cb[f] : 0.f;
#pragma unroll
            for (int rg = 0; rg < 4; ++rg) {
                int s = st * 16 + q * 4 + rg;
                float v = (f < FF) ? fmaxf(acc[st][fi][rg] + bias, 0.f) : 0.f;
                A2[s * A2P + f] = (short)f2bf(v);
            }
        }
#pragma unroll
    for (int it = 0; it < 5; ++it) {
        int seg = it * 4 + wv;
        if (seg < 17) g2lds16((const char*)fcwT2 + seg * 1024 + lane * 16,
                              (char*)B2 + seg * 1024);
    }
    __syncthreads();

    if (wv < 2) {
        v4f a2[4];
#pragma unroll
        for (int nt = 0; nt < 4; ++nt) a2[nt] = (v4f){0.f, 0.f, 0.f, 0.f};
#pragma unroll
        for (int ks = 0; ks < 4; ++ks) {
            v8s af = ldsld8(&A2[(wv * 16 + col) * A2P + ks * 32 + q * 8]);
#pragma unroll
            for (int nt = 0; nt < 4; ++nt) {
                v8s bt = ldsld8(&B2[(nt * 16 + col) * A2P + ks * 32 + q * 8]);
                a2[nt] = MFMA16(af, bt, a2[nt], 0, 0, 0);
            }
        }
        float fb0 = fcb[col], fb1 = fcb[16 + col], fb2 = fcb[32 + col];
        float fb3 = (col < 2) ? fcb[48 + col] : 0.f;
#pragma unroll
        for (int rg = 0; rg < 4; ++rg) {
            int s = s0 + wv * 16 + q * 4 + rg;
            float e0v = a2[0][rg] + fb0;
            float e1v = a2[1][rg] + fb1;
            float e2v = a2[2][rg] + fb2;
            float e3v = (col < 2) ? a2[3][rg] + fb3 : -1e30f;
            float m = fmaxf(fmaxf(e0v, e1v), fmaxf(e2v, e3v));
#pragma unroll
            for (int off = 1; off < 16; off <<= 1) m = fmaxf(m, __shfl_xor(m, off));
            int gidx = b * SS + s;
            if (col == 0) rmv[gidx] = m;
            int tg = tags[gidx];
            float* orow = expem + (size_t)gidx * TT;
            orow[col]      = __expf(e0v - m);
            orow[16 + col] = __expf(e1v - m);
            orow[32 + col] = __expf(e2v - m);
            if (col < 2) orow[48 + col] = __expf(e3v - m);
            if (tg == col)            emtag[gidx] = e0v;
            else if (tg == 16 + col)  emtag[gidx] = e1v;
            else if (tg == 32 + col)  emtag[gidx] = e2v;
            else if (col < 2 && tg == 48 + col) emtag[gidx] = e3v;
        }
    }
}

// ---------------------------------------------------------------------------
// Kernel B1: per-(batch,chunk) product of 16 step matrices via MFMA.
// C_c = (D_{t0+15} A^T)...(D_{t0} A^T), stored row-major bf16 (normalized by
// max, log-scale in lsR). grid (NC, BB), 64 threads (1 wave).
// LDS M layout: L[n][j] = M[j][n] (B-operand ready); A^T frags in registers.
// ---------------------------------------------------------------------------
__global__ __launch_bounds__(64) void chunk_kernel(
    const float* __restrict__ expem, const unsigned short* __restrict__ AT,
    const unsigned short* __restrict__ Ab,
    unsigned short* __restrict__ R, float* __restrict__ lsR)
{
    __shared__ __align__(16) short L[2][64 * MP];
    __shared__ __align__(16) float emL[CH][64];
    const int c = blockIdx.x, b = blockIdx.y;
    const int lane = threadIdx.x;
    const int col = lane & 15, q = lane >> 4;
    const int t0 = c * CH + 1;                       // first transition index
    const int nf = (c == NC - 1) ? (SS - 1 - (NC - 1) * CH) : CH;   // 16 or 15 factors

    // stage em rows (expem[t0+k][m]) into LDS, zero-padded
    for (int idx = lane; idx < CH * 64; idx += 64) {
        int k = idx >> 6, m = idx & 63;
        float v = 0.f;
        if (m < TT && k < nf) v = expem[((size_t)(b * SS + t0 + k)) * TT + m];
        emL[k][m] = v;
    }

    // A^T fragments (constant): af[jt][kc], rows j = jt*16+col, k contig
    v8s af[4][2];
#pragma unroll
    for (int jt = 0; jt < 4; ++jt)
#pragma unroll
        for (int kc = 0; kc < 2; ++kc)
            af[jt][kc] = *(const v8s*)(AT + (jt * 16 + col) * 64 + kc * 32 + q * 8);
    __syncthreads();

    // init: L[0][n][j] = A[n][j] * em0[j]   (lane = row n)
    {
        const v8s* arow = (const v8s*)(Ab + lane * 64);
#pragma unroll
        for (int g = 0; g < 8; ++g) {
            v8s a = arow[g];
            v8s o;
#pragma unroll
            for (int e = 0; e < 8; ++e)
                o[e] = (short)f2bf(bf2f(a[e]) * emL[0][g * 8 + e]);
            *(v8s*)&L[0][lane * MP + g * 8] = o;
        }
    }

    int cur = 0;
    for (int k = 1; k < nf; ++k) {
        __syncthreads();
        v8s bf[4][2];
#pragma unroll
        for (int nt = 0; nt < 4; ++nt)
#pragma unroll
            for (int kc = 0; kc < 2; ++kc)
                bf[nt][kc] = ldsld8(&L[cur][(nt * 16 + col) * MP + kc * 32 + q * 8]);
        v4f acc[4][4];
#pragma unroll
        for (int jt = 0; jt < 4; ++jt)
#pragma unroll
            for (int nt = 0; nt < 4; ++nt) {
                acc[jt][nt] = (v4f){0.f, 0.f, 0.f, 0.f};
                acc[jt][nt] = MFMA16(af[jt][0], bf[nt][0], acc[jt][nt], 0, 0, 0);
                acc[jt][nt] = MFMA16(af[jt][1], bf[nt][1], acc[jt][nt], 0, 0, 0);
            }
        if (k < nf - 1) {
            // epilogue -> LDS (next B operand): L'[n][j] = em_k[j] * P[j][n]
#pragma unroll
            for (int jt = 0; jt < 4; ++jt) {
                const float4 em4 = *(const float4*)&emL[k][jt * 16 + q * 4];
#pragma unroll
                for (int nt = 0; nt < 4; ++nt) {
                    short4 o;
                    o.x = (short)f2bf(acc[jt][nt][0] * em4.x);
                    o.y = (short)f2bf(acc[jt][nt][1] * em4.y);
                    o.z = (short)f2bf(acc[jt][nt][2] * em4.z);
                    o.w = (short)f2bf(acc[jt][nt][3] * em4.w);
                    *(short4*)&L[cur ^ 1][(nt * 16 + col) * MP + jt * 16 + q * 4] = o;
                }
            }
            cur ^= 1;
        } else {
            // final epilogue: normalize by max, store row-major to global
            float vals[4][4][4];
            float mx = 0.f;
#pragma unroll
            for (int jt = 0; jt < 4; ++jt) {
                const float4 em4 = *(const float4*)&emL[k][jt * 16 + q * 4];
#pragma unroll
                for (int nt = 0; nt < 4; ++nt) {
                    vals[jt][nt][0] = acc[jt][nt][0] * em4.x;
                    vals[jt][nt][1] = acc[jt][nt][1] * em4.y;
                    vals[jt][nt][2] = acc[jt][nt][2] * em4.z;
                    vals[jt][nt][3] = acc[jt][nt][3] * em4.w;
#pragma unroll
                    for (int r = 0; r < 4; ++r) mx = fmaxf(mx, vals[jt][nt][r]);
                }
            }
#pragma unroll
            for (int off = 1; off < 64; off <<= 1) mx = fmaxf(mx, __shfl_xor(mx, off));
            mx = fmaxf(mx, 1e-37f);
            float inv = 1.f / mx;
            unsigned short* Rc = R + ((size_t)(b * NC + c) << 12);
#pragma unroll
            for (int jt = 0; jt < 4; ++jt)
#pragma unroll
                for (int nt = 0; nt < 4; ++nt)
#pragma unroll
                    for (int r = 0; r < 4; ++r)
                        Rc[(jt * 16 + q * 4 + r) * 64 + nt * 16 + col] =
                            f2bf(vals[jt][nt][r] * inv);
            if (lane == 0) lsR[b * NC + c] = __logf(mx);
        }
    }
}

// ---------------------------------------------------------------------------
// Kernel B2: per-batch chain over NC chunk matrices (matvec each), -> lzpart.
// grid BB, 64 threads. Lane i owns row i; p broadcast from LDS.
// ---------------------------------------------------------------------------
__global__ __launch_bounds__(64) void chain_kernel(
    const float* __restrict__ expem, const unsigned short* __restrict__ R,
    const float* __restrict__ lsR, const float* __restrict__ start,
    const float* __restrict__ endt, float* __restrict__ lzpart)
{
    __shared__ __align__(16) float pvec[64];
    const int b = blockIdx.x, i = threadIdx.x;

    pvec[i] = (i < TT) ? __expf(start[i]) * expem[((size_t)(b * SS)) * TT + i] : 0.f;

    const unsigned short* Rb = R + ((size_t)(b * NC) << 12);
    v8s rowb[8];
#pragma unroll
    for (int g = 0; g < 8; ++g) rowb[g] = *(const v8s*)(Rb + i * 64 + g * 8);
    float logacc = 0.f;
    __syncthreads();

    for (int c = 0; c < NC; ++c) {
        float rw[64];
#pragma unroll
        for (int g = 0; g < 8; ++g)
#pragma unroll
            for (int e = 0; e < 8; ++e) rw[g * 8 + e] = bf2f(rowb[g][e]);
        if (c + 1 < NC) {
            const unsigned short* Rn = Rb + ((size_t)(c + 1) << 12);
#pragma unroll
            for (int g = 0; g < 8; ++g) rowb[g] = *(const v8s*)(Rn + i * 64 + g * 8);
        }
        float acc = 0.f;
        const float4* pv = (const float4*)pvec;
#pragma unroll
        for (int g = 0; g < 16; ++g) {
            float4 p4 = pv[g];
            acc = fmaf(rw[g * 4 + 0], p4.x, acc);
            acc = fmaf(rw[g * 4 + 1], p4.y, acc);
            acc = fmaf(rw[g * 4 + 2], p4.z, acc);
            acc = fmaf(rw[g * 4 + 3], p4.w, acc);
        }
        float mx = acc;
#pragma unroll
        for (int off = 1; off < 64; off <<= 1) mx = fmaxf(mx, __shfl_xor(mx, off));
        mx = fmaxf(mx, 1e-37f);
        logacc += __logf(mx) + lsR[b * NC + c];
        __syncthreads();
        pvec[i] = acc * (1.f / mx);
        __syncthreads();
    }

    float sv = (i < TT) ? pvec[i] * __expf(endt[i]) : 0.f;
#pragma unroll
    for (int off = 1; off < 64; off <<= 1) sv += __shfl_xor(sv, off);
    if (i == 0) lzpart[b] = logacc + __logf(sv);
}

// ---------------------------------------------------------------------------
// Kernel C: numerator + combine + total sum -> scalar
// ---------------------------------------------------------------------------
__global__ __launch_bounds__(256) void final_kernel(
    const float* __restrict__ emtag, const float* __restrict__ rmv,
    const int* __restrict__ tags, const float* __restrict__ tr,
    const float* __restrict__ start, const float* __restrict__ endt,
    const float* __restrict__ lzpart, float* __restrict__ out)
{
    __shared__ float redN[256], redR[256], nllsh[BB];
    const int tid = threadIdx.x;
    const int b   = tid >> 3;
    const int sl  = tid & 7;
    const int base = b * SS + sl * 64;

    float accN = 0.f, accR = 0.f;
    for (int k = 0; k < 64; ++k) {
        int s = sl * 64 + k;
        accN += emtag[base + k];
        accR += rmv[base + k];
        int tg = tags[base + k];
        if (s < SS - 1) accN += tr[tg * TT + tags[base + k + 1]];
    }
    redN[tid] = accN; redR[tid] = accR;
    __syncthreads();

    if (sl == 0) {
        float tn = 0.f, trm = 0.f;
#pragma unroll
        for (int k = 0; k < 8; ++k) { tn += redN[b * 8 + k]; trm += redR[b * 8 + k]; }
        float num = tn + start[tags[b * SS]] + endt[tags[b * SS + SS - 1]];
        float lz  = trm + lzpart[b];
        nllsh[b] = lz - num;
    }
    __syncthreads();
    if (tid < 64) {
        float v = (tid < BB) ? nllsh[tid] : 0.f;
#pragma unroll
        for (int off = 1; off < 64; off <<= 1) v += __shfl_xor(v, off);
        if (tid == 0) out[0] = v;
    }
}

extern "C" void kernel_launch(void* const* d_in, const int* in_sizes, int n_in,
                              void* d_out, int out_size, void* d_ws, size_t ws_size,
                              hipStream_t stream)
{
    const int*   x    = (const int*)d_in[0];
    const int*   tags = (const int*)d_in[1];
    const float* emb  = (const float*)d_in[2];
    const float* cw   = (const float*)d_in[3];
    const float* cb   = (const float*)d_in[4];
    const float* fcw  = (const float*)d_in[5];
    const float* fcb  = (const float*)d_in[6];
    const float* st   = (const float*)d_in[7];
    const float* en   = (const float*)d_in[8];
    const float* tr   = (const float*)d_in[9];

    unsigned short* wB2   = (unsigned short*)d_ws;            // 122880
    unsigned short* fcwT2 = wB2 + 6 * 128 * BKC;              // 8704
    unsigned short* ATm   = fcwT2 + 64 * A2P;                 // 4096
    unsigned short* Abm   = ATm + 4096;                       // 4096
    unsigned short* Rm    = Abm + 4096;                       // 32*32*4096 = 4194304
    float* fbase  = (float*)(Rm + (size_t)BB * NC * 4096);
    float* expem  = fbase;                                    // 819200
    float* rmv    = expem + (size_t)BB * SS * TT;             // 16384
    float* emtag  = rmv + BB * SS;                            // 16384
    float* lsR    = emtag + BB * SS;                          // 1024
    float* lzpart = lsR + BB * NC;                            // 32

    prep_kernel<<<dim3(64), 256, 0, stream>>>(tr, cw, fcw, wB2, fcwT2, ATm, Abm);
    emis_kernel<<<dim3(16, BB), 256, 0, stream>>>(x, emb, wB2, cb, fcwT2, fcb,
                                                  tags, expem, rmv, emtag);
    chunk_kernel<<<dim3(NC, BB), 64, 0, stream>>>(expem, ATm, Abm, Rm, lsR);
    chain_kernel<<<dim3(BB), 64, 0, stream>>>(expem, Rm, lsR, st, en, lzpart);
    final_kernel<<<dim3(1), 256, 0, stream>>>(emtag, rmv, tags, tr, st, en,
                                              lzpart, (float*)d_out);
}

// Round 5
// 249.803 us; speedup vs baseline: 3.1246x; 1.0267x over previous
//
#include <hip/hip_runtime.h>
#include <hip/hip_bf16.h>
#include <math.h>

#define BB 32
#define SS 512
#define EE 300
#define FF 100
#define TT 50
#define CH 16            // steps per chunk-product (15 multiplies, overflow-safe)
#define NC 32            // chunks = 512/16

typedef __attribute__((ext_vector_type(8))) short v8s;   // 8 bf16
typedef __attribute__((ext_vector_type(4))) float v4f;   // 4 f32
#define MFMA16 __builtin_amdgcn_mfma_f32_16x16x32_bf16

#define AP 328           // emb LDS stride (shorts): 164 words -> 2-way max (free)
#define NCH 10           // conv K-chunks of 96
#define CKS 3            // k-steps per chunk
#define CHB (128 * 96)   // shorts per conv B chunk buffer (24576 B)
#define A2P 152          // feat LDS stride (shorts): 76 words -> ~2-way (free)
#define MP 72            // chunk-product LDS row stride (bf16)

__device__ inline unsigned short f2bf(float v) {
    unsigned u = __float_as_uint(v);
    unsigned r = u + 0x7fff + ((u >> 16) & 1);
    return (unsigned short)(r >> 16);
}
__device__ inline float bf2f(short s) {
    return __uint_as_float(((unsigned)(unsigned short)s) << 16);
}
__device__ inline v8s ldsld8(const short* p) {
    return *(const v8s*)__builtin_assume_aligned(p, 16);
}
__device__ inline void g2lds16(const void* g, void* l) {
    __builtin_amdgcn_global_load_lds(
        (const __attribute__((address_space(1))) unsigned int*)g,
        (__attribute__((address_space(3))) unsigned int*)l, 16, 0, 0);
}

// ---------------------------------------------------------------------------
// Kernel 0: fragment-linear bf16 weight layouts + bf16 exp(trans) matrices.
// wB2: 10 chunks x 3 ksteps x 8 ftiles x 64 lanes x 8 elems.
//   element(ch,sl,ft,col,q,e) = cw[n=ft*16+col][ee][kk], gk=ch*96+sl*32+q*8+e,
//   kk=gk/320, ee=gk%320 (zero-pad n>=100, ee>=300).
// fcwT2: 4 ksteps x 4 ttiles x 64 x 8: fcw[t=nt*16+col][f=ks*32+q*8+e].
// ---------------------------------------------------------------------------
__global__ void prep_kernel(const float* __restrict__ tr, const float* __restrict__ cw,
                            const float* __restrict__ fcw,
                            unsigned short* __restrict__ wB2,
                            unsigned short* __restrict__ fcwT2,
                            unsigned short* __restrict__ AT,
                            unsigned short* __restrict__ Ab)
{
    const int gid = blockIdx.x * 256 + threadIdx.x;
    const int gs  = 64 * 256;
    for (int idx = gid; idx < NCH * CKS * 8 * 512; idx += gs) {
        int e = idx & 7, p = (idx >> 3) & 63, blk = idx >> 9;
        int ch = blk / 24, rem = blk - ch * 24;
        int sl = rem >> 3, ft = rem & 7;
        int col = p >> 2, q = p & 3;
        int n  = ft * 16 + col;
        int gk = ch * 96 + sl * 32 + q * 8 + e;
        int kk = gk / 320, ee = gk - kk * 320;
        float v = (n < FF && ee < EE) ? cw[n * 900 + ee * 3 + kk] : 0.f;
        wB2[idx] = f2bf(v);
    }
    for (int idx = gid; idx < 16 * 512; idx += gs) {
        int e = idx & 7, p = (idx >> 3) & 63, blk = idx >> 9;
        int ks = blk >> 2, nt = blk & 3;
        int col = p >> 2, q = p & 3;
        int t = nt * 16 + col, f = ks * 32 + q * 8 + e;
        float v = (t < TT && f < FF) ? fcw[t * FF + f] : 0.f;
        fcwT2[idx] = f2bf(v);
    }
    for (int idx = gid; idx < 64 * 64; idx += gs) {
        int r = idx >> 6, c2 = idx & 63;
        AT[idx] = (r < TT && c2 < TT) ? f2bf(__expf(tr[c2 * TT + r])) : 0;
        Ab[idx] = (r < TT && c2 < TT) ? f2bf(__expf(tr[r * TT + c2])) : 0;
    }
}

// ---------------------------------------------------------------------------
// Kernel A: MFMA conv(K=3) + FC, double-buffered weight DMA, fragment-linear
// conflict-free B reads. grid (16, 32), 256 threads (4 waves).
// ---------------------------------------------------------------------------
__global__ __launch_bounds__(256, 2) void emis_kernel(
    const int* __restrict__ x, const float* __restrict__ emb,
    const unsigned short* __restrict__ wB2, const float* __restrict__ cb,
    const unsigned short* __restrict__ fcwT2, const float* __restrict__ fcb,
    const int* __restrict__ tags,
    float* __restrict__ expem, float* __restrict__ rmv, float* __restrict__ emtag)
{
    __shared__ __align__(16) short ldsA[34 * AP];       // 22304 B
    __shared__ __align__(16) short ldsB[2][CHB];        // 2 x 24576 B

    const int b    = blockIdx.y;
    const int s0   = blockIdx.x * 32;
    const int tid  = threadIdx.x;
    const int wv   = tid >> 6;
    const int lane = tid & 63;
    const int col  = lane & 15;
    const int q    = lane >> 4;
    const int bofs = ((col << 2) | q) << 3;             // fragment-linear lane offset

    // kick off DMA of conv chunk 0 (overlaps the A gather below)
#pragma unroll
    for (int it = 0; it < 6; ++it) {
        int seg = it * 4 + wv;
        g2lds16((const char*)wB2 + seg * 1024 + lane * 16,
                (char*)ldsB[0] + seg * 1024);
    }

    // stage A: 34 emb rows -> bf16 (zero halo rows, zero cols 300..319)
    for (int g = tid; g < 34 * 75; g += 256) {
        int r = g / 75, eg = g - r * 75; int e0 = eg * 4;
        int gsq = s0 - 1 + r;
        short4 o;
        if (gsq >= 0 && gsq < SS) {
            int xr = x[b * SS + gsq];
            const float4 v = *(const float4*)(emb + (size_t)xr * EE + e0);
            o = make_short4((short)f2bf(v.x), (short)f2bf(v.y),
                            (short)f2bf(v.z), (short)f2bf(v.w));
        } else o = make_short4(0, 0, 0, 0);
        *(short4*)&ldsA[r * AP + e0] = o;
    }
    if (tid < 34 * 5) {
        int r = tid / 5, c0 = 300 + (tid % 5) * 4;
        *(short4*)&ldsA[r * AP + c0] = make_short4(0, 0, 0, 0);
    }
    __syncthreads();   // A staged + chunk-0 DMA drained

    v4f acc[2][2];
#pragma unroll
    for (int a = 0; a < 2; ++a)
#pragma unroll
        for (int f = 0; f < 2; ++f) acc[a][f] = (v4f){0.f, 0.f, 0.f, 0.f};

    const int ftA = wv * 2, ftB = wv * 2 + 1;
    for (int ch = 0; ch < NCH; ++ch) {
        if (ch < NCH - 1) {   // prefetch next chunk into the other buffer
            const char* g = (const char*)(wB2 + (size_t)(ch + 1) * CHB);
            char* l = (char*)ldsB[(ch + 1) & 1];
#pragma unroll
            for (int it = 0; it < 6; ++it) {
                int seg = it * 4 + wv;
                g2lds16(g + seg * 1024 + lane * 16, l + seg * 1024);
            }
        }
        const short* Bc = ldsB[ch & 1];
#pragma unroll
        for (int sl = 0; sl < CKS; ++sl) {
            int gk = ch * 96 + sl * 32;
            int kk = (gk >= 640) ? 2 : (gk >= 320 ? 1 : 0);
            int e0 = gk - kk * 320;
            v8s a0 = ldsld8(&ldsA[(col + kk) * AP + e0 + q * 8]);
            v8s a1 = ldsld8(&ldsA[(16 + col + kk) * AP + e0 + q * 8]);
            v8s b0 = ldsld8(&Bc[((sl * 8 + ftA) << 9) + bofs]);
            v8s b1 = ldsld8(&Bc[((sl * 8 + ftB) << 9) + bofs]);
            acc[0][0] = MFMA16(a0, b0, acc[0][0], 0, 0, 0);
            acc[0][1] = MFMA16(a0, b1, acc[0][1], 0, 0, 0);
            acc[1][0] = MFMA16(a1, b0, acc[1][0], 0, 0, 0);
            acc[1][1] = MFMA16(a1, b1, acc[1][1], 0, 0, 0);
        }
        __syncthreads();   // done reading Bc; next chunk's DMA drained
    }

    // feat (bias+relu, bf16) -> ldsB[0]; FC weights DMA -> ldsB[1]
    short* A2 = ldsB[0];
    short* B2 = ldsB[1];
#pragma unroll
    for (int it = 0; it < 4; ++it) {
        int seg = it * 4 + wv;
        g2lds16((const char*)fcwT2 + seg * 1024 + lane * 16,
                (char*)B2 + seg * 1024);
    }
#pragma unroll
    for (int st = 0; st < 2; ++st)
#pragma unroll
        for (int fi = 0; fi < 2; ++fi) {
            int f = (wv * 2 + fi) * 16 + col;
            float bias = (f < FF) ? cb[f] : 0.f;
#pragma unroll
            for (int rg = 0; rg < 4; ++rg) {
                int s = st * 16 + q * 4 + rg;
                float v = (f < FF) ? fmaxf(acc[st][fi][rg] + bias, 0.f) : 0.f;
                A2[s * A2P + f] = (short)f2bf(v);
            }
        }
    __syncthreads();

    // FC MFMA + epilogue (waves 0,1; wave = s-tile)
    if (wv < 2) {
        v4f a2[4];
#pragma unroll
        for (int nt = 0; nt < 4; ++nt) a2[nt] = (v4f){0.f, 0.f, 0.f, 0.f};
#pragma unroll
        for (int ks = 0; ks < 4; ++ks) {
            v8s af = ldsld8(&A2[(wv * 16 + col) * A2P + ks * 32 + q * 8]);
#pragma unroll
            for (int nt = 0; nt < 4; ++nt) {
                v8s bt = ldsld8(&B2[((ks * 4 + nt) << 9) + bofs]);
                a2[nt] = MFMA16(af, bt, a2[nt], 0, 0, 0);
            }
        }
        float fb0 = fcb[col], fb1 = fcb[16 + col], fb2 = fcb[32 + col];
        float fb3 = (col < 2) ? fcb[48 + col] : 0.f;
#pragma unroll
        for (int rg = 0; rg < 4; ++rg) {
            int s = s0 + wv * 16 + q * 4 + rg;
            float e0v = a2[0][rg] + fb0;
            float e1v = a2[1][rg] + fb1;
            float e2v = a2[2][rg] + fb2;
            float e3v = (col < 2) ? a2[3][rg] + fb3 : -1e30f;
            float m = fmaxf(fmaxf(e0v, e1v), fmaxf(e2v, e3v));
#pragma unroll
            for (int off = 1; off < 16; off <<= 1) m = fmaxf(m, __shfl_xor(m, off));
            int gidx = b * SS + s;
            if (col == 0) rmv[gidx] = m;
            int tg = tags[gidx];
            float* orow = expem + (size_t)gidx * TT;
            orow[col]      = __expf(e0v - m);
            orow[16 + col] = __expf(e1v - m);
            orow[32 + col] = __expf(e2v - m);
            if (col < 2) orow[48 + col] = __expf(e3v - m);
            if (tg == col)            emtag[gidx] = e0v;
            else if (tg == 16 + col)  emtag[gidx] = e1v;
            else if (tg == 32 + col)  emtag[gidx] = e2v;
            else if (col < 2 && tg == 48 + col) emtag[gidx] = e3v;
        }
    }
}

// ---------------------------------------------------------------------------
// Kernel B1: per-(batch,chunk) product of 16 step matrices via MFMA. (as R4)
// ---------------------------------------------------------------------------
__global__ __launch_bounds__(64) void chunk_kernel(
    const float* __restrict__ expem, const unsigned short* __restrict__ AT,
    const unsigned short* __restrict__ Ab,
    unsigned short* __restrict__ R, float* __restrict__ lsR)
{
    __shared__ __align__(16) short L[2][64 * MP];
    __shared__ __align__(16) float emL[CH][64];
    const int c = blockIdx.x, b = blockIdx.y;
    const int lane = threadIdx.x;
    const int col = lane & 15, q = lane >> 4;
    const int t0 = c * CH + 1;
    const int nf = (c == NC - 1) ? (SS - 1 - (NC - 1) * CH) : CH;

    for (int idx = lane; idx < CH * 64; idx += 64) {
        int k = idx >> 6, m = idx & 63;
        float v = 0.f;
        if (m < TT && k < nf) v = expem[((size_t)(b * SS + t0 + k)) * TT + m];
        emL[k][m] = v;
    }

    v8s af[4][2];
#pragma unroll
    for (int jt = 0; jt < 4; ++jt)
#pragma unroll
        for (int kc = 0; kc < 2; ++kc)
            af[jt][kc] = *(const v8s*)(AT + (jt * 16 + col) * 64 + kc * 32 + q * 8);
    __syncthreads();

    {
        const v8s* arow = (const v8s*)(Ab + lane * 64);
#pragma unroll
        for (int g = 0; g < 8; ++g) {
            v8s a = arow[g];
            v8s o;
#pragma unroll
            for (int e = 0; e < 8; ++e)
                o[e] = (short)f2bf(bf2f(a[e]) * emL[0][g * 8 + e]);
            *(v8s*)&L[0][lane * MP + g * 8] = o;
        }
    }

    int cur = 0;
    for (int k = 1; k < nf; ++k) {
        __syncthreads();
        v8s bf[4][2];
#pragma unroll
        for (int nt = 0; nt < 4; ++nt)
#pragma unroll
            for (int kc = 0; kc < 2; ++kc)
                bf[nt][kc] = ldsld8(&L[cur][(nt * 16 + col) * MP + kc * 32 + q * 8]);
        v4f acc[4][4];
#pragma unroll
        for (int jt = 0; jt < 4; ++jt)
#pragma unroll
            for (int nt = 0; nt < 4; ++nt) {
                acc[jt][nt] = (v4f){0.f, 0.f, 0.f, 0.f};
                acc[jt][nt] = MFMA16(af[jt][0], bf[nt][0], acc[jt][nt], 0, 0, 0);
                acc[jt][nt] = MFMA16(af[jt][1], bf[nt][1], acc[jt][nt], 0, 0, 0);
            }
        if (k < nf - 1) {
#pragma unroll
            for (int jt = 0; jt < 4; ++jt) {
                const float4 em4 = *(const float4*)&emL[k][jt * 16 + q * 4];
#pragma unroll
                for (int nt = 0; nt < 4; ++nt) {
                    short4 o;
                    o.x = (short)f2bf(acc[jt][nt][0] * em4.x);
                    o.y = (short)f2bf(acc[jt][nt][1] * em4.y);
                    o.z = (short)f2bf(acc[jt][nt][2] * em4.z);
                    o.w = (short)f2bf(acc[jt][nt][3] * em4.w);
                    *(short4*)&L[cur ^ 1][(nt * 16 + col) * MP + jt * 16 + q * 4] = o;
                }
            }
            cur ^= 1;
        } else {
            float vals[4][4][4];
            float mx = 0.f;
#pragma unroll
            for (int jt = 0; jt < 4; ++jt) {
                const float4 em4 = *(const float4*)&emL[k][jt * 16 + q * 4];
#pragma unroll
                for (int nt = 0; nt < 4; ++nt) {
                    vals[jt][nt][0] = acc[jt][nt][0] * em4.x;
                    vals[jt][nt][1] = acc[jt][nt][1] * em4.y;
                    vals[jt][nt][2] = acc[jt][nt][2] * em4.z;
                    vals[jt][nt][3] = acc[jt][nt][3] * em4.w;
#pragma unroll
                    for (int r = 0; r < 4; ++r) mx = fmaxf(mx, vals[jt][nt][r]);
                }
            }
#pragma unroll
            for (int off = 1; off < 64; off <<= 1) mx = fmaxf(mx, __shfl_xor(mx, off));
            mx = fmaxf(mx, 1e-37f);
            float inv = 1.f / mx;
            unsigned short* Rc = R + ((size_t)(b * NC + c) << 12);
#pragma unroll
            for (int jt = 0; jt < 4; ++jt)
#pragma unroll
                for (int nt = 0; nt < 4; ++nt)
#pragma unroll
                    for (int r = 0; r < 4; ++r)
                        Rc[(jt * 16 + q * 4 + r) * 64 + nt * 16 + col] =
                            f2bf(vals[jt][nt][r] * inv);
            if (lane == 0) lsR[b * NC + c] = __logf(mx);
        }
    }
}

// ---------------------------------------------------------------------------
// Kernel B2: fused chain + numerator. grid BB, 256 threads.
// Wave 0: chain over NC chunk matrices (prefetch depth 3).
// Waves 1-3: gold-path numerator + rowmax sum (overlaps wave 0's latency).
// ---------------------------------------------------------------------------
__global__ __launch_bounds__(256) void chain_kernel(
    const float* __restrict__ expem, const unsigned short* __restrict__ R,
    const float* __restrict__ lsR, const float* __restrict__ start,
    const float* __restrict__ endt,
    const float* __restrict__ emtag, const float* __restrict__ rmv,
    const int* __restrict__ tags, const float* __restrict__ tr,
    float* __restrict__ nllpart)
{
    __shared__ __align__(16) float pvec[64];
    __shared__ float red[8];
    __shared__ float lzsh;
    const int b = blockIdx.x, tid = threadIdx.x;
    const int wv = tid >> 6, i = tid & 63;

    if (wv == 0) {
        // wave-coherent LDS use: single wave owns pvec, no block barrier needed
        pvec[i] = (i < TT) ? __expf(start[i]) * expem[((size_t)(b * SS)) * TT + i] : 0.f;
        const unsigned short* Rb = R + ((size_t)(b * NC) << 12);
        v8s rb[3][8];
#pragma unroll
        for (int pc = 0; pc < 3; ++pc)
#pragma unroll
            for (int g = 0; g < 8; ++g)
                rb[pc][g] = *(const v8s*)(Rb + ((size_t)pc << 12) + i * 64 + g * 8);
        float logacc = 0.f;
#pragma unroll
        for (int c = 0; c < NC; ++c) {
            const int slot = c % 3;
            float acc = 0.f;
            const float4* pv = (const float4*)pvec;
#pragma unroll
            for (int g = 0; g < 8; ++g) {
                v8s v = rb[slot][g];
                float4 pA = pv[g * 2], pB = pv[g * 2 + 1];
                acc = fmaf(bf2f(v[0]), pA.x, acc);
                acc = fmaf(bf2f(v[1]), pA.y, acc);
                acc = fmaf(bf2f(v[2]), pA.z, acc);
                acc = fmaf(bf2f(v[3]), pA.w, acc);
                acc = fmaf(bf2f(v[4]), pB.x, acc);
                acc = fmaf(bf2f(v[5]), pB.y, acc);
                acc = fmaf(bf2f(v[6]), pB.z, acc);
                acc = fmaf(bf2f(v[7]), pB.w, acc);
            }
            if (c + 3 < NC) {
                const unsigned short* Rn = Rb + ((size_t)(c + 3) << 12);
#pragma unroll
                for (int g = 0; g < 8; ++g)
                    rb[slot][g] = *(const v8s*)(Rn + i * 64 + g * 8);
            }
            float mx = acc;
#pragma unroll
            for (int off = 1; off < 64; off <<= 1) mx = fmaxf(mx, __shfl_xor(mx, off));
            mx = fmaxf(mx, 1e-37f);
            logacc += __logf(mx) + lsR[b * NC + c];
            pvec[i] = acc * (1.f / mx);
        }
        float sv = (i < TT) ? pvec[i] * __expf(endt[i]) : 0.f;
#pragma unroll
        for (int off = 1; off < 64; off <<= 1) sv += __shfl_xor(sv, off);
        if (i == 0) lzsh = logacc + __logf(sv);
    } else {
        float accN = 0.f, accR = 0.f;
        for (int s = tid - 64; s < SS; s += 192) {
            int gi = b * SS + s;
            accN += emtag[gi];
            accR += rmv[gi];
            int tg = tags[gi];
            if (s < SS - 1) accN += tr[tg * TT + tags[gi + 1]];
        }
#pragma unroll
        for (int off = 1; off < 64; off <<= 1) {
            accN += __shfl_xor(accN, off);
            accR += __shfl_xor(accR, off);
        }
        if (i == 0) { red[wv] = accN; red[4 + wv] = accR; }
    }
    __syncthreads();
    if (tid == 0) {
        float tn  = red[1] + red[2] + red[3];
        float trm = red[5] + red[6] + red[7];
        float num = tn + start[tags[b * SS]] + endt[tags[b * SS + SS - 1]];
        nllpart[b] = trm + lzsh - num;
    }
}

// ---------------------------------------------------------------------------
// Kernel C: sum 32 per-batch NLLs -> scalar
// ---------------------------------------------------------------------------
__global__ void final_kernel(const float* __restrict__ nllpart, float* __restrict__ out)
{
    int tid = threadIdx.x;
    float v = (tid < BB) ? nllpart[tid] : 0.f;
#pragma unroll
    for (int off = 1; off < 64; off <<= 1) v += __shfl_xor(v, off);
    if (tid == 0) out[0] = v;
}

extern "C" void kernel_launch(void* const* d_in, const int* in_sizes, int n_in,
                              void* d_out, int out_size, void* d_ws, size_t ws_size,
                              hipStream_t stream)
{
    const int*   x    = (const int*)d_in[0];
    const int*   tags = (const int*)d_in[1];
    const float* emb  = (const float*)d_in[2];
    const float* cw   = (const float*)d_in[3];
    const float* cb   = (const float*)d_in[4];
    const float* fcw  = (const float*)d_in[5];
    const float* fcb  = (const float*)d_in[6];
    const float* st   = (const float*)d_in[7];
    const float* en   = (const float*)d_in[8];
    const float* tr   = (const float*)d_in[9];

    unsigned short* wB2   = (unsigned short*)d_ws;            // 122880 sh
    unsigned short* fcwT2 = wB2 + NCH * CKS * 8 * 512;        // 8192 sh
    unsigned short* ATm   = fcwT2 + 16 * 512;                 // 4096 sh
    unsigned short* Abm   = ATm + 4096;                       // 4096 sh
    unsigned short* Rm    = Abm + 4096;                       // BB*NC*4096 sh = 8 MB
    float* fbase   = (float*)(Rm + (size_t)BB * NC * 4096);
    float* expem   = fbase;                                   // 819200
    float* rmv     = expem + (size_t)BB * SS * TT;            // 16384
    float* emtag   = rmv + BB * SS;                           // 16384
    float* lsR     = emtag + BB * SS;                         // 1024
    float* nllpart = lsR + BB * NC;                           // 32

    prep_kernel<<<dim3(64), 256, 0, stream>>>(tr, cw, fcw, wB2, fcwT2, ATm, Abm);
    emis_kernel<<<dim3(16, BB), 256, 0, stream>>>(x, emb, wB2, cb, fcwT2, fcb,
                                                  tags, expem, rmv, emtag);
    chunk_kernel<<<dim3(NC, BB), 64, 0, stream>>>(expem, ATm, Abm, Rm, lsR);
    chain_kernel<<<dim3(BB), 256, 0, stream>>>(expem, Rm, lsR, st, en,
                                               emtag, rmv, tags, tr, nllpart);
    final_kernel<<<dim3(1), 64, 0, stream>>>(nllpart, (float*)d_out);
}

// Round 6
// 241.093 us; speedup vs baseline: 3.2374x; 1.0361x over previous
//
#include <hip/hip_runtime.h>
#include <hip/hip_bf16.h>
#include <math.h>

#define BB 32
#define SS 512
#define EE 300
#define FF 100
#define TT 50
#define CH 16            // steps per chunk-product (15 multiplies, overflow-safe)
#define NC 32            // chunks = 512/16

typedef __attribute__((ext_vector_type(8))) short v8s;   // 8 bf16
typedef __attribute__((ext_vector_type(4))) float v4f;   // 4 f32
#define MFMA16 __builtin_amdgcn_mfma_f32_16x16x32_bf16

#define AP 328           // emb LDS stride (shorts): 164 words -> 2-way max (free)
#define NCH 10           // conv K-chunks of 96
#define CKS 3            // k-steps per chunk
#define CHB (128 * 96)   // shorts per conv B chunk buffer (24576 B)
#define A2P 136          // feat LDS stride (shorts): 68 words -> 2-way (free)
#define MP 72            // chunk-product LDS row stride (bf16)

__device__ inline unsigned short f2bf(float v) {
    unsigned u = __float_as_uint(v);
    unsigned r = u + 0x7fff + ((u >> 16) & 1);
    return (unsigned short)(r >> 16);
}
__device__ inline float bf2f(short s) {
    return __uint_as_float(((unsigned)(unsigned short)s) << 16);
}
__device__ inline unsigned pkbf2(float a, float b) {   // v_cvt_pk_bf16_f32
    __hip_bfloat162 h = __float22bfloat162_rn(make_float2(a, b));
    return *(unsigned*)&h;
}
__device__ inline v8s ldsld8(const short* p) {
    return *(const v8s*)__builtin_assume_aligned(p, 16);
}
__device__ inline void g2lds16(const void* g, void* l) {
    __builtin_amdgcn_global_load_lds(
        (const __attribute__((address_space(1))) unsigned int*)g,
        (__attribute__((address_space(3))) unsigned int*)l, 16, 0, 0);
}

// ---------------------------------------------------------------------------
// Kernel 0: fragment-linear bf16 weight layouts + bf16 exp(trans) matrices
// + zero the atomic accumulator/counter used by chain_kernel.
// ---------------------------------------------------------------------------
__global__ void prep_kernel(const float* __restrict__ tr, const float* __restrict__ cw,
                            const float* __restrict__ fcw,
                            unsigned short* __restrict__ wB2,
                            unsigned short* __restrict__ fcwT2,
                            unsigned short* __restrict__ AT,
                            unsigned short* __restrict__ Ab,
                            float* __restrict__ accum, unsigned* __restrict__ cnt)
{
    const int gid = blockIdx.x * 256 + threadIdx.x;
    const int gs  = 64 * 256;
    if (gid == 0) { *accum = 0.f; *cnt = 0u; }
    for (int idx = gid; idx < NCH * CKS * 8 * 512; idx += gs) {
        int e = idx & 7, p = (idx >> 3) & 63, blk = idx >> 9;
        int ch = blk / 24, rem = blk - ch * 24;
        int sl = rem >> 3, ft = rem & 7;
        int col = p >> 2, q = p & 3;
        int n  = ft * 16 + col;
        int gk = ch * 96 + sl * 32 + q * 8 + e;
        int kk = gk / 320, ee = gk - kk * 320;
        float v = (n < FF && ee < EE) ? cw[n * 900 + ee * 3 + kk] : 0.f;
        wB2[idx] = f2bf(v);
    }
    for (int idx = gid; idx < 16 * 512; idx += gs) {
        int e = idx & 7, p = (idx >> 3) & 63, blk = idx >> 9;
        int ks = blk >> 2, nt = blk & 3;
        int col = p >> 2, q = p & 3;
        int t = nt * 16 + col, f = ks * 32 + q * 8 + e;
        float v = (t < TT && f < FF) ? fcw[t * FF + f] : 0.f;
        fcwT2[idx] = f2bf(v);
    }
    for (int idx = gid; idx < 64 * 64; idx += gs) {
        int r = idx >> 6, c2 = idx & 63;
        AT[idx] = (r < TT && c2 < TT) ? f2bf(__expf(tr[c2 * TT + r])) : 0;
        Ab[idx] = (r < TT && c2 < TT) ? f2bf(__expf(tr[r * TT + c2])) : 0;
    }
}

// ---------------------------------------------------------------------------
// Kernel A: MFMA conv(K=3) + FC. Single-buffered weights (47 KB LDS ->
// 3 blocks/CU), staging gather with forced memory-level parallelism.
// grid (16, 32), 256 threads (4 waves).
// ---------------------------------------------------------------------------
__global__ __launch_bounds__(256, 3) void emis_kernel(
    const int* __restrict__ x, const float* __restrict__ emb,
    const unsigned short* __restrict__ wB2, const float* __restrict__ cb,
    const unsigned short* __restrict__ fcwT2, const float* __restrict__ fcb,
    const int* __restrict__ tags,
    float* __restrict__ expem, float* __restrict__ rmv, float* __restrict__ emtag)
{
    __shared__ __align__(16) short ldsA[34 * AP];       // 22304 B (reused as feat)
    __shared__ __align__(16) short ldsB[CHB];           // 24576 B (weights)

    const int b    = blockIdx.y;
    const int s0   = blockIdx.x * 32;
    const int tid  = threadIdx.x;
    const int wv   = tid >> 6;
    const int lane = tid & 63;
    const int col  = lane & 15;
    const int q    = lane >> 4;
    const int bofs = ((col << 2) | q) << 3;             // fragment-linear lane offset

    // DMA conv chunk 0 (overlaps the A-gather below)
#pragma unroll
    for (int it = 0; it < 6; ++it) {
        int seg = it * 4 + wv;
        g2lds16((const char*)wB2 + seg * 1024 + lane * 16,
                (char*)ldsB + seg * 1024);
    }

    // ---- stage A with explicit MLP: all x-loads, then all emb gathers ----
    int   xr[10], ofs[10], e0a[10];
#pragma unroll
    for (int it = 0; it < 10; ++it) {
        int g = tid + it * 256;
        int r = g / 75, eg = g - r * 75;
        int e0 = eg * 4;
        int src = s0 - 1 + r;
        bool v = (g < 2550) && (src >= 0) && (src < SS);
        xr[it]  = v ? x[b * SS + src] : -1;
        ofs[it] = r * AP + e0;
        e0a[it] = e0;
    }
    float4 vv[10];
#pragma unroll
    for (int it = 0; it < 10; ++it)
        vv[it] = (xr[it] >= 0)
               ? *(const float4*)(emb + (size_t)xr[it] * EE + e0a[it])
               : make_float4(0.f, 0.f, 0.f, 0.f);
#pragma unroll
    for (int it = 0; it < 10; ++it) {
        int g = tid + it * 256;
        if (g < 2550) {
            unsigned lo = pkbf2(vv[it].x, vv[it].y);
            unsigned hi = pkbf2(vv[it].z, vv[it].w);
            *(uint2*)&ldsA[ofs[it]] = make_uint2(lo, hi);
        }
    }
    if (tid < 34 * 5) {
        int r = tid / 5, c0 = 300 + (tid % 5) * 4;
        *(short4*)&ldsA[r * AP + c0] = make_short4(0, 0, 0, 0);
    }

    v4f acc[2][2];
#pragma unroll
    for (int a = 0; a < 2; ++a)
#pragma unroll
        for (int f = 0; f < 2; ++f) acc[a][f] = (v4f){0.f, 0.f, 0.f, 0.f};

    const int ftA = wv * 2, ftB = wv * 2 + 1;
    for (int ch = 0; ch < NCH; ++ch) {
        __syncthreads();   // DMA for chunk ch drained (+ A staged on ch=0)
#pragma unroll
        for (int sl = 0; sl < CKS; ++sl) {
            int gk = ch * 96 + sl * 32;
            int kk = (gk >= 640) ? 2 : (gk >= 320 ? 1 : 0);
            int e0 = gk - kk * 320;
            v8s a0 = ldsld8(&ldsA[(col + kk) * AP + e0 + q * 8]);
            v8s a1 = ldsld8(&ldsA[(16 + col + kk) * AP + e0 + q * 8]);
            v8s b0 = ldsld8(&ldsB[((sl * 8 + ftA) << 9) + bofs]);
            v8s b1 = ldsld8(&ldsB[((sl * 8 + ftB) << 9) + bofs]);
            acc[0][0] = MFMA16(a0, b0, acc[0][0], 0, 0, 0);
            acc[0][1] = MFMA16(a0, b1, acc[0][1], 0, 0, 0);
            acc[1][0] = MFMA16(a1, b0, acc[1][0], 0, 0, 0);
            acc[1][1] = MFMA16(a1, b1, acc[1][1], 0, 0, 0);
        }
        __syncthreads();   // all waves done reading ldsB
        if (ch < NCH - 1) {   // refill buffer for next chunk
            const char* g = (const char*)(wB2 + (size_t)(ch + 1) * CHB);
#pragma unroll
            for (int it = 0; it < 6; ++it) {
                int seg = it * 4 + wv;
                g2lds16(g + seg * 1024 + lane * 16, (char*)ldsB + seg * 1024);
            }
        }
    }

    // FC weights DMA into ldsB; feat (bias+relu, bf16) into ldsA (dead)
    short* A2 = ldsA;
    short* B2 = ldsB;
#pragma unroll
    for (int it = 0; it < 4; ++it) {
        int seg = it * 4 + wv;
        g2lds16((const char*)fcwT2 + seg * 1024 + lane * 16,
                (char*)B2 + seg * 1024);
    }
#pragma unroll
    for (int st = 0; st < 2; ++st)
#pragma unroll
        for (int fi = 0; fi < 2; ++fi) {
            int f = (wv * 2 + fi) * 16 + col;
            float bias = (f < FF) ? cb[f] : 0.f;
#pragma unroll
            for (int rg = 0; rg < 4; ++rg) {
                int s = st * 16 + q * 4 + rg;
                float v = (f < FF) ? fmaxf(acc[st][fi][rg] + bias, 0.f) : 0.f;
                A2[s * A2P + f] = (short)f2bf(v);
            }
        }
    __syncthreads();

    // FC MFMA + epilogue (waves 0,1; wave = s-tile)
    if (wv < 2) {
        v4f a2[4];
#pragma unroll
        for (int nt = 0; nt < 4; ++nt) a2[nt] = (v4f){0.f, 0.f, 0.f, 0.f};
#pragma unroll
        for (int ks = 0; ks < 4; ++ks) {
            v8s af = ldsld8(&A2[(wv * 16 + col) * A2P + ks * 32 + q * 8]);
#pragma unroll
            for (int nt = 0; nt < 4; ++nt) {
                v8s bt = ldsld8(&B2[((ks * 4 + nt) << 9) + bofs]);
                a2[nt] = MFMA16(af, bt, a2[nt], 0, 0, 0);
            }
        }
        float fb0 = fcb[col], fb1 = fcb[16 + col], fb2 = fcb[32 + col];
        float fb3 = (col < 2) ? fcb[48 + col] : 0.f;
#pragma unroll
        for (int rg = 0; rg < 4; ++rg) {
            int s = s0 + wv * 16 + q * 4 + rg;
            float e0v = a2[0][rg] + fb0;
            float e1v = a2[1][rg] + fb1;
            float e2v = a2[2][rg] + fb2;
            float e3v = (col < 2) ? a2[3][rg] + fb3 : -1e30f;
            float m = fmaxf(fmaxf(e0v, e1v), fmaxf(e2v, e3v));
#pragma unroll
            for (int off = 1; off < 16; off <<= 1) m = fmaxf(m, __shfl_xor(m, off));
            int gidx = b * SS + s;
            if (col == 0) rmv[gidx] = m;
            int tg = tags[gidx];
            float* orow = expem + (size_t)gidx * TT;
            orow[col]      = __expf(e0v - m);
            orow[16 + col] = __expf(e1v - m);
            orow[32 + col] = __expf(e2v - m);
            if (col < 2) orow[48 + col] = __expf(e3v - m);
            if (tg == col)            emtag[gidx] = e0v;
            else if (tg == 16 + col)  emtag[gidx] = e1v;
            else if (tg == 32 + col)  emtag[gidx] = e2v;
            else if (col < 2 && tg == 48 + col) emtag[gidx] = e3v;
        }
    }
}

// ---------------------------------------------------------------------------
// Kernel B1: per-(batch,chunk) product of 16 step matrices via MFMA.
// Packed bf16 cvt in the per-iteration epilogue (issue-bound single wave).
// ---------------------------------------------------------------------------
__global__ __launch_bounds__(64) void chunk_kernel(
    const float* __restrict__ expem, const unsigned short* __restrict__ AT,
    const unsigned short* __restrict__ Ab,
    unsigned short* __restrict__ R, float* __restrict__ lsR)
{
    __shared__ __align__(16) short L[2][64 * MP];
    __shared__ __align__(16) float emL[CH][64];
    const int c = blockIdx.x, b = blockIdx.y;
    const int lane = threadIdx.x;
    const int col = lane & 15, q = lane >> 4;
    const int t0 = c * CH + 1;
    const int nf = (c == NC - 1) ? (SS - 1 - (NC - 1) * CH) : CH;

    for (int idx = lane; idx < CH * 64; idx += 64) {
        int k = idx >> 6, m = idx & 63;
        float v = 0.f;
        if (m < TT && k < nf) v = expem[((size_t)(b * SS + t0 + k)) * TT + m];
        emL[k][m] = v;
    }

    v8s af[4][2];
#pragma unroll
    for (int jt = 0; jt < 4; ++jt)
#pragma unroll
        for (int kc = 0; kc < 2; ++kc)
            af[jt][kc] = *(const v8s*)(AT + (jt * 16 + col) * 64 + kc * 32 + q * 8);
    __syncthreads();

    {
        const v8s* arow = (const v8s*)(Ab + lane * 64);
#pragma unroll
        for (int g = 0; g < 8; ++g) {
            v8s a = arow[g];
            float f[8];
#pragma unroll
            for (int e = 0; e < 8; ++e) f[e] = bf2f(a[e]) * emL[0][g * 8 + e];
            uint4 o = make_uint4(pkbf2(f[0], f[1]), pkbf2(f[2], f[3]),
                                 pkbf2(f[4], f[5]), pkbf2(f[6], f[7]));
            *(uint4*)&L[0][lane * MP + g * 8] = o;
        }
    }

    int cur = 0;
    for (int k = 1; k < nf; ++k) {
        __syncthreads();
        v8s bf[4][2];
#pragma unroll
        for (int nt = 0; nt < 4; ++nt)
#pragma unroll
            for (int kc = 0; kc < 2; ++kc)
                bf[nt][kc] = ldsld8(&L[cur][(nt * 16 + col) * MP + kc * 32 + q * 8]);
        v4f acc[4][4];
#pragma unroll
        for (int jt = 0; jt < 4; ++jt)
#pragma unroll
            for (int nt = 0; nt < 4; ++nt) {
                acc[jt][nt] = (v4f){0.f, 0.f, 0.f, 0.f};
                acc[jt][nt] = MFMA16(af[jt][0], bf[nt][0], acc[jt][nt], 0, 0, 0);
                acc[jt][nt] = MFMA16(af[jt][1], bf[nt][1], acc[jt][nt], 0, 0, 0);
            }
        if (k < nf - 1) {
#pragma unroll
            for (int jt = 0; jt < 4; ++jt) {
                const float4 em4 = *(const float4*)&emL[k][jt * 16 + q * 4];
#pragma unroll
                for (int nt = 0; nt < 4; ++nt) {
                    uint2 o = make_uint2(
                        pkbf2(acc[jt][nt][0] * em4.x, acc[jt][nt][1] * em4.y),
                        pkbf2(acc[jt][nt][2] * em4.z, acc[jt][nt][3] * em4.w));
                    *(uint2*)&L[cur ^ 1][(nt * 16 + col) * MP + jt * 16 + q * 4] = o;
                }
            }
            cur ^= 1;
        } else {
            float vals[4][4][4];
            float mx = 0.f;
#pragma unroll
            for (int jt = 0; jt < 4; ++jt) {
                const float4 em4 = *(const float4*)&emL[k][jt * 16 + q * 4];
#pragma unroll
                for (int nt = 0; nt < 4; ++nt) {
                    vals[jt][nt][0] = acc[jt][nt][0] * em4.x;
                    vals[jt][nt][1] = acc[jt][nt][1] * em4.y;
                    vals[jt][nt][2] = acc[jt][nt][2] * em4.z;
                    vals[jt][nt][3] = acc[jt][nt][3] * em4.w;
#pragma unroll
                    for (int r = 0; r < 4; ++r) mx = fmaxf(mx, vals[jt][nt][r]);
                }
            }
#pragma unroll
            for (int off = 1; off < 64; off <<= 1) mx = fmaxf(mx, __shfl_xor(mx, off));
            mx = fmaxf(mx, 1e-37f);
            float inv = 1.f / mx;
            unsigned short* Rc = R + ((size_t)(b * NC + c) << 12);
#pragma unroll
            for (int jt = 0; jt < 4; ++jt)
#pragma unroll
                for (int nt = 0; nt < 4; ++nt)
#pragma unroll
                    for (int r = 0; r < 4; ++r)
                        Rc[(jt * 16 + q * 4 + r) * 64 + nt * 16 + col] =
                            f2bf(vals[jt][nt][r] * inv);
            if (lane == 0) lsR[b * NC + c] = __logf(mx);
        }
    }
}

// ---------------------------------------------------------------------------
// Kernel B2: fused chain + numerator + atomic finish (no separate sum kernel).
// grid BB, 256 threads. Wave 0: chain (prefetch depth 3). Waves 1-3: numerator.
// Last block (device-scope counter) writes the scalar output.
// ---------------------------------------------------------------------------
__global__ __launch_bounds__(256) void chain_kernel(
    const float* __restrict__ expem, const unsigned short* __restrict__ R,
    const float* __restrict__ lsR, const float* __restrict__ start,
    const float* __restrict__ endt,
    const float* __restrict__ emtag, const float* __restrict__ rmv,
    const int* __restrict__ tags, const float* __restrict__ tr,
    float* __restrict__ accum, unsigned* __restrict__ cnt,
    float* __restrict__ out)
{
    __shared__ __align__(16) float pvec[64];
    __shared__ float red[8];
    __shared__ float lzsh;
    const int b = blockIdx.x, tid = threadIdx.x;
    const int wv = tid >> 6, i = tid & 63;

    if (wv == 0) {
        pvec[i] = (i < TT) ? __expf(start[i]) * expem[((size_t)(b * SS)) * TT + i] : 0.f;
        const unsigned short* Rb = R + ((size_t)(b * NC) << 12);
        v8s rb[3][8];
#pragma unroll
        for (int pc = 0; pc < 3; ++pc)
#pragma unroll
            for (int g = 0; g < 8; ++g)
                rb[pc][g] = *(const v8s*)(Rb + ((size_t)pc << 12) + i * 64 + g * 8);
        float logacc = 0.f;
#pragma unroll
        for (int c = 0; c < NC; ++c) {
            const int slot = c % 3;
            float acc = 0.f;
            const float4* pv = (const float4*)pvec;
#pragma unroll
            for (int g = 0; g < 8; ++g) {
                v8s v = rb[slot][g];
                float4 pA = pv[g * 2], pB = pv[g * 2 + 1];
                acc = fmaf(bf2f(v[0]), pA.x, acc);
                acc = fmaf(bf2f(v[1]), pA.y, acc);
                acc = fmaf(bf2f(v[2]), pA.z, acc);
                acc = fmaf(bf2f(v[3]), pA.w, acc);
                acc = fmaf(bf2f(v[4]), pB.x, acc);
                acc = fmaf(bf2f(v[5]), pB.y, acc);
                acc = fmaf(bf2f(v[6]), pB.z, acc);
                acc = fmaf(bf2f(v[7]), pB.w, acc);
            }
            if (c + 3 < NC) {
                const unsigned short* Rn = Rb + ((size_t)(c + 3) << 12);
#pragma unroll
                for (int g = 0; g < 8; ++g)
                    rb[slot][g] = *(const v8s*)(Rn + i * 64 + g * 8);
            }
            float mx = acc;
#pragma unroll
            for (int off = 1; off < 64; off <<= 1) mx = fmaxf(mx, __shfl_xor(mx, off));
            mx = fmaxf(mx, 1e-37f);
            logacc += __logf(mx) + lsR[b * NC + c];
            pvec[i] = acc * (1.f / mx);
        }
        float sv = (i < TT) ? pvec[i] * __expf(endt[i]) : 0.f;
#pragma unroll
        for (int off = 1; off < 64; off <<= 1) sv += __shfl_xor(sv, off);
        if (i == 0) lzsh = logacc + __logf(sv);
    } else {
        float accN = 0.f, accR = 0.f;
        for (int s = tid - 64; s < SS; s += 192) {
            int gi = b * SS + s;
            accN += emtag[gi];
            accR += rmv[gi];
            int tg = tags[gi];
            if (s < SS - 1) accN += tr[tg * TT + tags[gi + 1]];
        }
#pragma unroll
        for (int off = 1; off < 64; off <<= 1) {
            accN += __shfl_xor(accN, off);
            accR += __shfl_xor(accR, off);
        }
        if (i == 0) { red[wv] = accN; red[4 + wv] = accR; }
    }
    __syncthreads();
    if (tid == 0) {
        float tn  = red[1] + red[2] + red[3];
        float trm = red[5] + red[6] + red[7];
        float num = tn + start[tags[b * SS]] + endt[tags[b * SS + SS - 1]];
        float nll = trm + lzsh - num;
        atomicAdd(accum, nll);
        __threadfence();
        unsigned old = atomicAdd(cnt, 1u);
        if (old == BB - 1) out[0] = atomicAdd(accum, 0.f);
    }
}

extern "C" void kernel_launch(void* const* d_in, const int* in_sizes, int n_in,
                              void* d_out, int out_size, void* d_ws, size_t ws_size,
                              hipStream_t stream)
{
    const int*   x    = (const int*)d_in[0];
    const int*   tags = (const int*)d_in[1];
    const float* emb  = (const float*)d_in[2];
    const float* cw   = (const float*)d_in[3];
    const float* cb   = (const float*)d_in[4];
    const float* fcw  = (const float*)d_in[5];
    const float* fcb  = (const float*)d_in[6];
    const float* st   = (const float*)d_in[7];
    const float* en   = (const float*)d_in[8];
    const float* tr   = (const float*)d_in[9];

    unsigned short* wB2   = (unsigned short*)d_ws;            // 122880 sh
    unsigned short* fcwT2 = wB2 + NCH * CKS * 8 * 512;        // 8192 sh
    unsigned short* ATm   = fcwT2 + 16 * 512;                 // 4096 sh
    unsigned short* Abm   = ATm + 4096;                       // 4096 sh
    unsigned short* Rm    = Abm + 4096;                       // BB*NC*4096 sh = 8 MB
    float* fbase   = (float*)(Rm + (size_t)BB * NC * 4096);
    float* expem   = fbase;                                   // 819200
    float* rmv     = expem + (size_t)BB * SS * TT;            // 16384
    float* emtag   = rmv + BB * SS;                           // 16384
    float* lsR     = emtag + BB * SS;                         // 1024
    float* accum   = lsR + BB * NC;                           // 1
    unsigned* cnt  = (unsigned*)(accum + 1);                  // 1

    prep_kernel<<<dim3(64), 256, 0, stream>>>(tr, cw, fcw, wB2, fcwT2, ATm, Abm,
                                              accum, cnt);
    emis_kernel<<<dim3(16, BB), 256, 0, stream>>>(x, emb, wB2, cb, fcwT2, fcb,
                                                  tags, expem, rmv, emtag);
    chunk_kernel<<<dim3(NC, BB), 64, 0, stream>>>(expem, ATm, Abm, Rm, lsR);
    chain_kernel<<<dim3(BB), 256, 0, stream>>>(expem, Rm, lsR, st, en,
                                               emtag, rmv, tags, tr,
                                               accum, cnt, (float*)d_out);
}